// Round 3
// baseline (501.676 us; speedup 1.0000x reference)
//
#include <hip/hip_runtime.h>
#include <hip/hip_bf16.h>
#include <hip/hip_cooperative_groups.h>

namespace cg = cooperative_groups;

#define BB 4
#define NN 8192
#define DD 512
#define EE 8
#define OUTD 512
#define TOPM 1024
#define EPSV 1e-6f
#define ITERS 8

using s16x8 = __attribute__((ext_vector_type(8))) short;
using f32x4 = __attribute__((ext_vector_type(4))) float;

__device__ __forceinline__ unsigned short f2bf(float f) {
  unsigned u = __float_as_uint(f);
  return (unsigned short)((u + 0x7FFFu + ((u >> 16) & 1u)) >> 16);
}

__device__ __forceinline__ void gll16(const void* g, void* l) {
  __builtin_amdgcn_global_load_lds((const __attribute__((address_space(1))) void*)g,
                                   (__attribute__((address_space(3))) void*)l, 16, 0, 0);
}

// ---------------- gate logits -> t0 = log(max(x@gw, eps)); also x -> bf16 ----------------
__global__ __launch_bounds__(256) void k_gate(const float* __restrict__ x,
                                              const float* __restrict__ gw,
                                              float* __restrict__ t0,
                                              unsigned short* __restrict__ xbf) {
  const int lane = threadIdx.x & 63;
  const int wid  = threadIdx.x >> 6;
  const long row = (long)blockIdx.x * 4 + wid;   // B*N rows, grid=8192
  const float* xr = x + row * DD + lane * 8;
  float4 xa = *(const float4*)(xr);
  float4 xb = *(const float4*)(xr + 4);
  float xv[8] = {xa.x, xa.y, xa.z, xa.w, xb.x, xb.y, xb.z, xb.w};

  s16x8 xo;
#pragma unroll
  for (int j = 0; j < 8; ++j) xo[j] = (short)f2bf(xv[j]);
  *(s16x8*)(xbf + row * DD + lane * 8) = xo;

  float acc[8] = {0.f,0.f,0.f,0.f,0.f,0.f,0.f,0.f};
  const float* gbase = gw + (lane * 8) * EE;
#pragma unroll
  for (int j = 0; j < 8; ++j) {
    float4 g0 = *(const float4*)(gbase + j * EE);
    float4 g1 = *(const float4*)(gbase + j * EE + 4);
    acc[0] += xv[j] * g0.x; acc[1] += xv[j] * g0.y;
    acc[2] += xv[j] * g0.z; acc[3] += xv[j] * g0.w;
    acc[4] += xv[j] * g1.x; acc[5] += xv[j] * g1.y;
    acc[6] += xv[j] * g1.z; acc[7] += xv[j] * g1.w;
  }
#pragma unroll
  for (int off = 32; off; off >>= 1) {
#pragma unroll
    for (int e = 0; e < 8; ++e) acc[e] += __shfl_xor(acc[e], off);
  }
  if (lane < 8) t0[row * EE + lane] = logf(fmaxf(acc[lane], EPSV));
}

// ---------------- experts f32 [e][k][n] -> bf16 transposed [e][n][k] ----------------
__global__ __launch_bounds__(256) void k_wt(const float* __restrict__ W,
                                            unsigned short* __restrict__ WT) {
  __shared__ float tl[32][33];
  const int e = blockIdx.z, k0 = blockIdx.y * 32, n0 = blockIdx.x * 32;
  const int ty = threadIdx.x >> 5, tx = threadIdx.x & 31;
  const float* src = W + ((long)e * DD + k0) * OUTD + n0;
#pragma unroll
  for (int j = 0; j < 4; ++j)
    tl[ty + j * 8][tx] = src[(long)(ty + j * 8) * OUTD + tx];
  __syncthreads();
  unsigned short* dst = WT + ((long)e * OUTD + n0) * DD + k0;
#pragma unroll
  for (int j = 0; j < 4; ++j)
    dst[(long)(ty + j * 8) * DD + tx] = f2bf(tl[tx][ty + j * 8]);
}

// ---------------- cooperative fused Sinkhorn: 128 blocks, 1 row/thread ----------------
__global__ __launch_bounds__(256) void k_sink2(const float* __restrict__ t0,
                                               float* __restrict__ R,
                                               float* __restrict__ C,
                                               float* __restrict__ pm,   // [2][BB][32][EE]
                                               float* __restrict__ ps) { // [2][BB][32][EE]
  cg::grid_group grid = cg::this_grid();
  const int g = blockIdx.x;          // 128 = BB*32
  const int b = g >> 5, s = g & 31;
  const int tid = threadIdx.x;       // 256
  const int wv = tid >> 6, ln = tid & 63;
  const int n = s * 256 + tid;
  const float* p = t0 + ((long)b * NN + n) * EE;
  float4 v0 = *(const float4*)p, v1 = *(const float4*)(p + 4);
  float tv[8] = {v0.x, v0.y, v0.z, v0.w, v1.x, v1.y, v1.z, v1.w};
  float r = 0.f;
  __shared__ float rm[4][8], rs[4][8];
  __shared__ float Csh[8];
  for (int it = 0; it < ITERS; ++it) {
    // per-chunk col partials: LSE_n over this block's 256 rows, per e
#pragma unroll
    for (int e = 0; e < 8; ++e) {
      float v = tv[e] - r;
      float M = v;
#pragma unroll
      for (int o = 32; o; o >>= 1) M = fmaxf(M, __shfl_xor(M, o));
      float sv = expf(v - M);
#pragma unroll
      for (int o = 32; o; o >>= 1) sv += __shfl_xor(sv, o);
      if (ln == 0) { rm[wv][e] = M; rs[wv][e] = sv; }
    }
    __syncthreads();
    if (tid < 8) {
      float M = rm[0][tid], S = rs[0][tid];
#pragma unroll
      for (int q = 1; q < 4; ++q) {
        float mo = rm[q][tid], so = rs[q][tid];
        float Mx = fmaxf(M, mo);
        S = S * expf(M - Mx) + so * expf(mo - Mx);
        M = Mx;
      }
      const int idx = (((it & 1) * BB + b) * 32 + s) * EE + tid;
      pm[idx] = M;
      ps[idx] = S;
    }
    __threadfence();
    grid.sync();
    // every block combines its batch's 32 chunk partials -> C (in LDS)
    if (tid < 8) {
      const float* qm = pm + ((it & 1) * BB + b) * 32 * EE + tid;
      const float* qs = ps + ((it & 1) * BB + b) * 32 * EE + tid;
      float M = qm[0], S = qs[0];
      for (int q = 1; q < 32; ++q) {
        float mo = qm[q * EE], so = qs[q * EE];
        float Mx = fmaxf(M, mo);
        S = S * expf(M - Mx) + so * expf(mo - Mx);
        M = Mx;
      }
      Csh[tid] = M + logf(S);
    }
    __syncthreads();
    float c8[8];
#pragma unroll
    for (int e2 = 0; e2 < 8; ++e2) c8[e2] = Csh[e2];
    // row step (register-local)
    float mx = tv[0] - c8[0];
#pragma unroll
    for (int e2 = 1; e2 < 8; ++e2) mx = fmaxf(mx, tv[e2] - c8[e2]);
    float ss = 0.f;
#pragma unroll
    for (int e2 = 0; e2 < 8; ++e2) ss += expf(tv[e2] - c8[e2] - mx);
    r = mx + logf(ss);
  }
  R[(long)b * NN + n] = r;
  if (s == 0 && tid < 8) C[b * EE + tid] = Csh[tid];
}

// ---------------- exact top-1024 per (b,e) column via radix select ----------------
__global__ __launch_bounds__(1024) void k_topk(const float* __restrict__ t0,
                                               const float* __restrict__ R,
                                               int* __restrict__ expert_of) {
  __shared__ unsigned key[NN];
  __shared__ int hist[256];
  __shared__ int bcast[2];
  __shared__ int wsum[16];
  const int b = blockIdx.x >> 3, e = blockIdx.x & 7;
  const int tid = threadIdx.x;
  const int wv = tid >> 6, ln = tid & 63;
  const float* t = t0 + (long)b * NN * EE + e;
  const float* Rb = R + b * NN;
  for (int n = tid; n < NN; n += 1024) {
    float f = t[n * EE] - Rb[n];
    unsigned u = __float_as_uint(f);
    u = (u & 0x80000000u) ? ~u : (u | 0x80000000u);   // sortable: larger u = larger f
    key[n] = u;
  }
  __syncthreads();
  unsigned prefix = 0, mask = 0;
  int k = TOPM;
  for (int shift = 24; shift >= 0; shift -= 8) {
    if (tid < 256) hist[tid] = 0;
    __syncthreads();
    for (int n = tid; n < NN; n += 1024) {
      unsigned u = key[n];
      if ((u & mask) == prefix) atomicAdd(&hist[(u >> shift) & 255], 1);
    }
    __syncthreads();
    // parallel suffix-sum over 256 bins (Hillis-Steele)
    for (int d = 1; d < 256; d <<= 1) {
      int add = 0;
      if (tid < 256 - d) add = hist[tid + d];
      __syncthreads();
      if (tid < 256) hist[tid] += add;
      __syncthreads();
    }
    if (tid < 256) {
      int sv = hist[tid];
      int sv1 = (tid < 255) ? hist[tid + 1] : 0;
      if (sv >= k && sv1 < k) { bcast[0] = k - sv1; bcast[1] = tid; }
    }
    __syncthreads();
    k = bcast[0];
    prefix |= ((unsigned)bcast[1]) << shift;
    mask |= (255u << shift);
    __syncthreads();
  }
  const unsigned theta = prefix;
  const int need = k;                  // ties (==theta) to take, lowest index first
  const int base = tid * 8;            // contiguous chunks -> deterministic index order
  int c = 0;
#pragma unroll
  for (int j = 0; j < 8; ++j) if (key[base + j] == theta) ++c;
  // wave-level inclusive scan of tie counts
  int inc = c;
#pragma unroll
  for (int d = 1; d < 64; d <<= 1) {
    int o = __shfl_up(inc, d);
    if (ln >= d) inc += o;
  }
  if (ln == 63) wsum[wv] = inc;
  __syncthreads();
  if (tid == 0) {
    int runv = 0;
    for (int i = 0; i < 16; ++i) { int t2 = wsum[i]; wsum[i] = runv; runv += t2; }
  }
  __syncthreads();
  int run = wsum[wv] + inc - c;        // exclusive prefix of this thread's ties
  int* eo = expert_of + b * NN;
  for (int j = 0; j < 8; ++j) {
    int n = base + j;
    unsigned u = key[n];
    bool sel = false;
    if (u > theta) sel = true;
    else if (u == theta) { if (run < need) sel = true; ++run; }
    if (sel) atomicMax(&eo[n], e);     // np scatter: largest expert index wins
  }
}

// ---------------- compact per-(b,e) token lists + gate values ----------------
__global__ __launch_bounds__(256) void k_build(const int* __restrict__ expert_of,
                                               const float* __restrict__ t0,
                                               const float* __restrict__ R,
                                               const float* __restrict__ C,
                                               int* __restrict__ counts,
                                               int* __restrict__ lists,
                                               float* __restrict__ gvals) {
  const long i = (long)blockIdx.x * 256 + threadIdx.x;
  const int e = expert_of[i];
  if (e < 0) return;
  const int b = (int)(i >> 13);
  const int n = (int)(i & (NN - 1));
  const int be = b * EE + e;
  const int pos = atomicAdd(&counts[be], 1);
  const int slot = be * TOPM + pos;
  lists[slot] = n;
  gvals[slot] = expf(t0[i * EE + e] - C[be] - R[i]);
}

// ---------------- zero output rows of unselected tokens ----------------
__global__ __launch_bounds__(256) void k_zero(const int* __restrict__ eo,
                                              float* __restrict__ out) {
  const int row = blockIdx.x * 4 + (threadIdx.x >> 6);
  if (eo[row] >= 0) return;
  const int ln = threadIdx.x & 63;
  float4 z = make_float4(0.f, 0.f, 0.f, 0.f);
  float4* p = (float4*)(out + (long)row * OUTD) + ln;
  p[0] = z; p[64] = z;
}

// ---------------- gathered bf16 MFMA GEMM: out[tok,:] = g * x[tok,:] @ W[e] ----------------
__global__ __launch_bounds__(256) void k_gemm(const unsigned short* __restrict__ xbf,
                                              const unsigned short* __restrict__ WT,
                                              const int* __restrict__ counts,
                                              const int* __restrict__ lists,
                                              const float* __restrict__ gvals,
                                              float* __restrict__ out) {
  const int be = blockIdx.z;
  const int b = be >> 3, e = be & 7;
  const int cnt = counts[be];
  const int r0 = blockIdx.y * 128;
  if (r0 >= cnt) return;
  const int c0 = blockIdx.x * 128;

  __shared__ unsigned short As[128 * 32];   // [row][k] bf16, k-slot XOR-swizzled
  __shared__ unsigned short Bs[128 * 32];   // [col][k] bf16 (from WT), same swizzle
  __shared__ int   rowTok[128];
  __shared__ float rowG[128];

  const int tid = threadIdx.x;
  if (tid < 128) {
    int r = r0 + tid;
    rowTok[tid] = (r < cnt) ? lists[be * TOPM + r] : -1;
    rowG[tid]   = (r < cnt) ? gvals[be * TOPM + r] : 0.f;
  }
  __syncthreads();

  const int w = tid >> 6, l = tid & 63;
  const int c_a = 2 * w, c_b = 2 * w + 1;
  const int rr = l >> 2;
  const int slot = l & 3;
  const int ra0 = c_a * 16 + rr;
  const int ra1 = c_b * 16 + rr;
  const int kg0 = slot ^ ((ra0 >> 1) & 3);   // pre-swizzled global k-chunk (involution)
  const int kg1 = slot ^ ((ra1 >> 1) & 3);
  int tA0 = rowTok[ra0]; if (tA0 < 0) tA0 = 0;
  int tA1 = rowTok[ra1]; if (tA1 < 0) tA1 = 0;
  const unsigned short* gA0 = xbf + ((long)b * NN + tA0) * DD + kg0 * 8;
  const unsigned short* gA1 = xbf + ((long)b * NN + tA1) * DD + kg1 * 8;
  const unsigned short* gB0 = WT + ((long)e * OUTD + c0 + ra0) * DD + kg0 * 8;
  const unsigned short* gB1 = WT + ((long)e * OUTD + c0 + ra1) * DD + kg1 * 8;
  unsigned short* lA0 = As + c_a * 512;
  unsigned short* lA1 = As + c_b * 512;
  unsigned short* lB0 = Bs + c_a * 512;
  unsigned short* lB1 = Bs + c_b * 512;

  const int wr = w >> 1, wc = w & 1;
  const int fr = l & 15, fq = l >> 4;
  int aoff[4], boff[4];
#pragma unroll
  for (int m = 0; m < 4; ++m) {
    int row = wr * 64 + m * 16 + fr;
    aoff[m] = row * 32 + (fq ^ ((row >> 1) & 3)) * 8;   // swizzled read matches staged layout
    int col = wc * 64 + m * 16 + fr;
    boff[m] = col * 32 + (fq ^ ((col >> 1) & 3)) * 8;
  }

  f32x4 acc[4][4] = {};

  gll16(gA0, lA0); gll16(gA1, lA1);
  gll16(gB0, lB0); gll16(gB1, lB1);

  for (int ks = 0; ks < 16; ++ks) {
    __syncthreads();
    s16x8 af[4], bfr[4];
#pragma unroll
    for (int m = 0; m < 4; ++m) af[m] = *(const s16x8*)(As + aoff[m]);
#pragma unroll
    for (int n = 0; n < 4; ++n) bfr[n] = *(const s16x8*)(Bs + boff[n]);
    __syncthreads();
    if (ks < 15) {
      int off = (ks + 1) * 32;
      gll16(gA0 + off, lA0); gll16(gA1 + off, lA1);
      gll16(gB0 + off, lB0); gll16(gB1 + off, lB1);
    }
#pragma unroll
    for (int m = 0; m < 4; ++m)
#pragma unroll
      for (int n = 0; n < 4; ++n)
        acc[m][n] = __builtin_amdgcn_mfma_f32_16x16x32_bf16(af[m], bfr[n], acc[m][n], 0, 0, 0);
  }

  // epilogue: C/D layout col=lane&15, row=(lane>>4)*4+reg
#pragma unroll
  for (int m = 0; m < 4; ++m) {
    int rbase = wr * 64 + m * 16 + fq * 4;
    int tok[4]; float g[4];
#pragma unroll
    for (int j = 0; j < 4; ++j) { tok[j] = rowTok[rbase + j]; g[j] = rowG[rbase + j]; }
#pragma unroll
    for (int n = 0; n < 4; ++n) {
      int col = c0 + wc * 64 + n * 16 + fr;
#pragma unroll
      for (int j = 0; j < 4; ++j) {
        if (tok[j] >= 0)
          out[((long)b * NN + tok[j]) * OUTD + col] = acc[m][n][j] * g[j];
      }
    }
  }
}

extern "C" void kernel_launch(void* const* d_in, const int* in_sizes, int n_in,
                              void* d_out, int out_size, void* d_ws, size_t ws_size,
                              hipStream_t stream) {
  const float* x  = (const float*)d_in[0];
  const float* gw = (const float*)d_in[1];
  const float* ex = (const float*)d_in[2];
  float* out = (float*)d_out;

  char* wsb = (char*)d_ws;
  float*          t0     = (float*)(wsb);                          // 1 MiB
  unsigned short* xbf    = (unsigned short*)(wsb + (1l << 20));    // 32 MiB
  unsigned short* WT     = (unsigned short*)(wsb + (33l << 20));   // 4 MiB
  const long base = 37l << 20;
  float*          R      = (float*)(wsb + base);                           // 128 KiB
  int*            eo     = (int*)  (wsb + base + (128l << 10));            // 128 KiB
  int*            lists  = (int*)  (wsb + base + (256l << 10));            // 128 KiB
  float*          gvals  = (float*)(wsb + base + (384l << 10));            // 128 KiB
  float*          C      = (float*)(wsb + base + (512l << 10));            // 32 B
  int*            counts = (int*)  (wsb + base + (512l << 10) + 1024);     // 128 B
  float*          pm     = (float*)(wsb + base + (512l << 10) + 2048);     // 8 KiB
  float*          ps     = (float*)(wsb + base + (512l << 10) + 2048 + 8192); // 8 KiB

  hipMemsetAsync(eo, 0xFF, (size_t)BB * NN * 4, stream);
  hipMemsetAsync(counts, 0, (size_t)BB * EE * 4, stream);

  k_gate<<<(BB * NN) / 4, 256, 0, stream>>>(x, gw, t0, xbf);
  k_wt<<<dim3(OUTD / 32, DD / 32, EE), 256, 0, stream>>>(ex, WT);

  {
    void* ka[] = {(void*)&t0, (void*)&R, (void*)&C, (void*)&pm, (void*)&ps};
    hipLaunchCooperativeKernel((void*)k_sink2, dim3(BB * 32), dim3(256), ka, 0, stream);
  }

  k_topk<<<BB * EE, 1024, 0, stream>>>(t0, R, eo);
  k_build<<<(BB * NN) / 256, 256, 0, stream>>>(eo, t0, R, C, counts, lists, gvals);
  k_zero<<<(BB * NN) / 4, 256, 0, stream>>>(eo, out);
  k_gemm<<<dim3(OUTD / 128, TOPM / 128, BB * EE), 256, 0, stream>>>(xbf, WT, counts, lists, gvals, out);
}

// Round 4
// 283.896 us; speedup vs baseline: 1.7671x; 1.7671x over previous
//
#include <hip/hip_runtime.h>
#include <hip/hip_bf16.h>

#define BB 4
#define NN 8192
#define DD 512
#define EE 8
#define OUTD 512
#define TOPM 1024
#define EPSV 1e-6f
#define ITERS 8
#define SB 8            // sinkhorn blocks per batch

using s16x8 = __attribute__((ext_vector_type(8))) short;
using f32x4 = __attribute__((ext_vector_type(4))) float;

__device__ __forceinline__ unsigned short f2bf(float f) {
  unsigned u = __float_as_uint(f);
  return (unsigned short)((u + 0x7FFFu + ((u >> 16) & 1u)) >> 16);
}

__device__ __forceinline__ void gll16(const void* g, void* l) {
  __builtin_amdgcn_global_load_lds((const __attribute__((address_space(1))) void*)g,
                                   (__attribute__((address_space(3))) void*)l, 16, 0, 0);
}

// ---------------- gate logits -> t0 = log(max(x@gw, eps)); also x -> bf16 ----------------
__global__ __launch_bounds__(256) void k_gate(const float* __restrict__ x,
                                              const float* __restrict__ gw,
                                              float* __restrict__ t0,
                                              unsigned short* __restrict__ xbf) {
  const int lane = threadIdx.x & 63;
  const int wid  = threadIdx.x >> 6;
  const long row = (long)blockIdx.x * 4 + wid;   // B*N rows, grid=8192
  const float* xr = x + row * DD + lane * 8;
  float4 xa = *(const float4*)(xr);
  float4 xb = *(const float4*)(xr + 4);
  float xv[8] = {xa.x, xa.y, xa.z, xa.w, xb.x, xb.y, xb.z, xb.w};

  s16x8 xo;
#pragma unroll
  for (int j = 0; j < 8; ++j) xo[j] = (short)f2bf(xv[j]);
  *(s16x8*)(xbf + row * DD + lane * 8) = xo;

  float acc[8] = {0.f,0.f,0.f,0.f,0.f,0.f,0.f,0.f};
  const float* gbase = gw + (lane * 8) * EE;
#pragma unroll
  for (int j = 0; j < 8; ++j) {
    float4 g0 = *(const float4*)(gbase + j * EE);
    float4 g1 = *(const float4*)(gbase + j * EE + 4);
    acc[0] += xv[j] * g0.x; acc[1] += xv[j] * g0.y;
    acc[2] += xv[j] * g0.z; acc[3] += xv[j] * g0.w;
    acc[4] += xv[j] * g1.x; acc[5] += xv[j] * g1.y;
    acc[6] += xv[j] * g1.z; acc[7] += xv[j] * g1.w;
  }
#pragma unroll
  for (int off = 32; off; off >>= 1) {
#pragma unroll
    for (int e = 0; e < 8; ++e) acc[e] += __shfl_xor(acc[e], off);
  }
  if (lane < 8) t0[row * EE + lane] = logf(fmaxf(acc[lane], EPSV));
}

// ---------------- experts f32 [e][k][n] -> bf16 transposed [e][n][k] ----------------
__global__ __launch_bounds__(256) void k_wt(const float* __restrict__ W,
                                            unsigned short* __restrict__ WT) {
  __shared__ float tl[32][33];
  const int e = blockIdx.z, k0 = blockIdx.y * 32, n0 = blockIdx.x * 32;
  const int ty = threadIdx.x >> 5, tx = threadIdx.x & 31;
  const float* src = W + ((long)e * DD + k0) * OUTD + n0;
#pragma unroll
  for (int j = 0; j < 4; ++j)
    tl[ty + j * 8][tx] = src[(long)(ty + j * 8) * OUTD + tx];
  __syncthreads();
  unsigned short* dst = WT + ((long)e * OUTD + n0) * DD + k0;
#pragma unroll
  for (int j = 0; j < 4; ++j)
    dst[(long)(ty + j * 8) * DD + tx] = f2bf(tl[tx][ty + j * 8]);
}

// ---------------- fused Sinkhorn: 32 blocks, 1 row/thread, per-batch spin barrier ----------------
__global__ __launch_bounds__(1024) void k_sink3(const float* __restrict__ t0,
                                                float* __restrict__ R,
                                                float* __restrict__ C,
                                                float* __restrict__ pm,   // [2][BB][SB][EE]
                                                float* __restrict__ ps,   // [2][BB][SB][EE]
                                                int* __restrict__ cnt) {  // [ITERS][BB]
  const int g = blockIdx.x;            // 32 = BB*SB
  const int b = g >> 3, s = g & 7;
  const int tid = threadIdx.x;         // 1024
  const int wv = tid >> 6, ln = tid & 63;
  const int n = s * 1024 + tid;
  const float* p = t0 + ((long)b * NN + n) * EE;
  float4 v0 = *(const float4*)p, v1 = *(const float4*)(p + 4);
  float tv[8] = {v0.x, v0.y, v0.z, v0.w, v1.x, v1.y, v1.z, v1.w};
  float r = 0.f;
  __shared__ float rm[16][8], rs[16][8], Csh[8];
  for (int it = 0; it < ITERS; ++it) {
    // block-local per-e (M,S) over this block's 1024 rows
#pragma unroll
    for (int e = 0; e < 8; ++e) {
      float v = tv[e] - r;
      float M = v;
#pragma unroll
      for (int o = 32; o; o >>= 1) M = fmaxf(M, __shfl_xor(M, o));
      float sv = expf(v - M);
#pragma unroll
      for (int o = 32; o; o >>= 1) sv += __shfl_xor(sv, o);
      if (ln == 0) { rm[wv][e] = M; rs[wv][e] = sv; }
    }
    __syncthreads();
    if (tid < 8) {
      float M = rm[0][tid], S = rs[0][tid];
#pragma unroll
      for (int q = 1; q < 16; ++q) {
        float mo = rm[q][tid], so = rs[q][tid];
        float Mx = fmaxf(M, mo);
        S = S * expf(M - Mx) + so * expf(mo - Mx);
        M = Mx;
      }
      const int idx = (((it & 1) * BB + b) * SB + s) * EE + tid;
      __hip_atomic_store(&pm[idx], M, __ATOMIC_RELAXED, __HIP_MEMORY_SCOPE_AGENT);
      __hip_atomic_store(&ps[idx], S, __ATOMIC_RELAXED, __HIP_MEMORY_SCOPE_AGENT);
    }
    __syncthreads();   // drains vmcnt: partial stores are at the device coherence point
    if (tid == 0) {
      __hip_atomic_fetch_add(&cnt[it * BB + b], 1, __ATOMIC_RELEASE, __HIP_MEMORY_SCOPE_AGENT);
      while (__hip_atomic_load(&cnt[it * BB + b], __ATOMIC_ACQUIRE, __HIP_MEMORY_SCOPE_AGENT) < SB)
        __builtin_amdgcn_s_sleep(2);
    }
    __syncthreads();
    // combine this batch's SB partials (device-scope loads: per-XCD L2 non-coherent)
    if (tid < 8) {
      const float* qm = pm + ((it & 1) * BB + b) * SB * EE + tid;
      const float* qs = ps + ((it & 1) * BB + b) * SB * EE + tid;
      float M = __hip_atomic_load(&qm[0], __ATOMIC_RELAXED, __HIP_MEMORY_SCOPE_AGENT);
      float S = __hip_atomic_load(&qs[0], __ATOMIC_RELAXED, __HIP_MEMORY_SCOPE_AGENT);
#pragma unroll
      for (int q = 1; q < SB; ++q) {
        float mo = __hip_atomic_load(&qm[q * EE], __ATOMIC_RELAXED, __HIP_MEMORY_SCOPE_AGENT);
        float so = __hip_atomic_load(&qs[q * EE], __ATOMIC_RELAXED, __HIP_MEMORY_SCOPE_AGENT);
        float Mx = fmaxf(M, mo);
        S = S * expf(M - Mx) + so * expf(mo - Mx);
        M = Mx;
      }
      Csh[tid] = M + logf(S);
    }
    __syncthreads();
    float c8[8];
#pragma unroll
    for (int e2 = 0; e2 < 8; ++e2) c8[e2] = Csh[e2];
    // row step (register-local)
    float mx = tv[0] - c8[0];
#pragma unroll
    for (int e2 = 1; e2 < 8; ++e2) mx = fmaxf(mx, tv[e2] - c8[e2]);
    float ss = 0.f;
#pragma unroll
    for (int e2 = 0; e2 < 8; ++e2) ss += expf(tv[e2] - c8[e2] - mx);
    r = mx + logf(ss);
  }
  R[(long)b * NN + n] = r;
  if (s == 0 && tid < 8) C[b * EE + tid] = Csh[tid];
}

// ---------------- exact top-1024 per (b,e) column via radix select ----------------
__global__ __launch_bounds__(1024) void k_topk(const float* __restrict__ t0,
                                               const float* __restrict__ R,
                                               int* __restrict__ expert_of) {
  __shared__ unsigned key[NN];
  __shared__ int hist[256];
  __shared__ int bcast[2];
  __shared__ int wsum[16];
  const int b = blockIdx.x >> 3, e = blockIdx.x & 7;
  const int tid = threadIdx.x;
  const int wv = tid >> 6, ln = tid & 63;
  const float* t = t0 + (long)b * NN * EE + e;
  const float* Rb = R + b * NN;
  for (int n = tid; n < NN; n += 1024) {
    float f = t[n * EE] - Rb[n];
    unsigned u = __float_as_uint(f);
    u = (u & 0x80000000u) ? ~u : (u | 0x80000000u);   // sortable: larger u = larger f
    key[n] = u;
  }
  __syncthreads();
  unsigned prefix = 0, mask = 0;
  int k = TOPM;
  for (int shift = 24; shift >= 0; shift -= 8) {
    if (tid < 256) hist[tid] = 0;
    __syncthreads();
    for (int n = tid; n < NN; n += 1024) {
      unsigned u = key[n];
      if ((u & mask) == prefix) atomicAdd(&hist[(u >> shift) & 255], 1);
    }
    __syncthreads();
    // parallel suffix-sum over 256 bins (Hillis-Steele)
    for (int d = 1; d < 256; d <<= 1) {
      int add = 0;
      if (tid < 256 - d) add = hist[tid + d];
      __syncthreads();
      if (tid < 256) hist[tid] += add;
      __syncthreads();
    }
    if (tid < 256) {
      int sv = hist[tid];
      int sv1 = (tid < 255) ? hist[tid + 1] : 0;
      if (sv >= k && sv1 < k) { bcast[0] = k - sv1; bcast[1] = tid; }
    }
    __syncthreads();
    k = bcast[0];
    prefix |= ((unsigned)bcast[1]) << shift;
    mask |= (255u << shift);
    __syncthreads();
  }
  const unsigned theta = prefix;
  const int need = k;                  // ties (==theta) to take, lowest index first
  const int base = tid * 8;            // contiguous chunks -> deterministic index order
  int c = 0;
#pragma unroll
  for (int j = 0; j < 8; ++j) if (key[base + j] == theta) ++c;
  // wave-level inclusive scan of tie counts
  int inc = c;
#pragma unroll
  for (int d = 1; d < 64; d <<= 1) {
    int o = __shfl_up(inc, d);
    if (ln >= d) inc += o;
  }
  if (ln == 63) wsum[wv] = inc;
  __syncthreads();
  if (tid == 0) {
    int runv = 0;
    for (int i = 0; i < 16; ++i) { int t2 = wsum[i]; wsum[i] = runv; runv += t2; }
  }
  __syncthreads();
  int run = wsum[wv] + inc - c;        // exclusive prefix of this thread's ties
  int* eo = expert_of + b * NN;
  for (int j = 0; j < 8; ++j) {
    int n = base + j;
    unsigned u = key[n];
    bool sel = false;
    if (u > theta) sel = true;
    else if (u == theta) { if (run < need) sel = true; ++run; }
    if (sel) atomicMax(&eo[n], e);     // np scatter: largest expert index wins
  }
}

// ---------------- compact per-(b,e) token lists + gate values ----------------
__global__ __launch_bounds__(256) void k_build(const int* __restrict__ expert_of,
                                               const float* __restrict__ t0,
                                               const float* __restrict__ R,
                                               const float* __restrict__ C,
                                               int* __restrict__ counts,
                                               int* __restrict__ lists,
                                               float* __restrict__ gvals) {
  const long i = (long)blockIdx.x * 256 + threadIdx.x;
  const int e = expert_of[i];
  if (e < 0) return;
  const int b = (int)(i >> 13);
  const int n = (int)(i & (NN - 1));
  const int be = b * EE + e;
  const int pos = atomicAdd(&counts[be], 1);
  const int slot = be * TOPM + pos;
  lists[slot] = n;
  gvals[slot] = expf(t0[i * EE + e] - C[be] - R[i]);
}

// ---------------- zero output rows of unselected tokens ----------------
__global__ __launch_bounds__(256) void k_zero(const int* __restrict__ eo,
                                              float* __restrict__ out) {
  const int row = blockIdx.x * 4 + (threadIdx.x >> 6);
  if (eo[row] >= 0) return;
  const int ln = threadIdx.x & 63;
  float4 z = make_float4(0.f, 0.f, 0.f, 0.f);
  float4* p = (float4*)(out + (long)row * OUTD) + ln;
  p[0] = z; p[64] = z;
}

// ---------------- gathered bf16 MFMA GEMM: out[tok,:] = g * x[tok,:] @ W[e] ----------------
__global__ __launch_bounds__(256) void k_gemm(const unsigned short* __restrict__ xbf,
                                              const unsigned short* __restrict__ WT,
                                              const int* __restrict__ counts,
                                              const int* __restrict__ lists,
                                              const float* __restrict__ gvals,
                                              float* __restrict__ out) {
  const int be = blockIdx.z;
  const int b = be >> 3, e = be & 7;
  const int cnt = counts[be];
  const int r0 = blockIdx.y * 128;
  if (r0 >= cnt) return;
  const int c0 = blockIdx.x * 128;

  __shared__ unsigned short As[128 * 32];   // [row][k] bf16, k-slot XOR-swizzled
  __shared__ unsigned short Bs[128 * 32];   // [col][k] bf16 (from WT), same swizzle
  __shared__ int   rowTok[128];
  __shared__ float rowG[128];

  const int tid = threadIdx.x;
  if (tid < 128) {
    int r = r0 + tid;
    rowTok[tid] = (r < cnt) ? lists[be * TOPM + r] : -1;
    rowG[tid]   = (r < cnt) ? gvals[be * TOPM + r] : 0.f;
  }
  __syncthreads();

  const int w = tid >> 6, l = tid & 63;
  const int c_a = 2 * w, c_b = 2 * w + 1;
  const int rr = l >> 2;
  const int slot = l & 3;
  const int ra0 = c_a * 16 + rr;
  const int ra1 = c_b * 16 + rr;
  const int kg0 = slot ^ ((ra0 >> 1) & 3);   // pre-swizzled global k-chunk (involution)
  const int kg1 = slot ^ ((ra1 >> 1) & 3);
  int tA0 = rowTok[ra0]; if (tA0 < 0) tA0 = 0;
  int tA1 = rowTok[ra1]; if (tA1 < 0) tA1 = 0;
  const unsigned short* gA0 = xbf + ((long)b * NN + tA0) * DD + kg0 * 8;
  const unsigned short* gA1 = xbf + ((long)b * NN + tA1) * DD + kg1 * 8;
  const unsigned short* gB0 = WT + ((long)e * OUTD + c0 + ra0) * DD + kg0 * 8;
  const unsigned short* gB1 = WT + ((long)e * OUTD + c0 + ra1) * DD + kg1 * 8;
  unsigned short* lA0 = As + c_a * 512;
  unsigned short* lA1 = As + c_b * 512;
  unsigned short* lB0 = Bs + c_a * 512;
  unsigned short* lB1 = Bs + c_b * 512;

  const int wr = w >> 1, wc = w & 1;
  const int fr = l & 15, fq = l >> 4;
  int aoff[4], boff[4];
#pragma unroll
  for (int m = 0; m < 4; ++m) {
    int row = wr * 64 + m * 16 + fr;
    aoff[m] = row * 32 + (fq ^ ((row >> 1) & 3)) * 8;   // swizzled read matches staged layout
    int col = wc * 64 + m * 16 + fr;
    boff[m] = col * 32 + (fq ^ ((col >> 1) & 3)) * 8;
  }

  f32x4 acc[4][4] = {};

  gll16(gA0, lA0); gll16(gA1, lA1);
  gll16(gB0, lB0); gll16(gB1, lB1);

  for (int ks = 0; ks < 16; ++ks) {
    __syncthreads();
    s16x8 af[4], bfr[4];
#pragma unroll
    for (int m = 0; m < 4; ++m) af[m] = *(const s16x8*)(As + aoff[m]);
#pragma unroll
    for (int n = 0; n < 4; ++n) bfr[n] = *(const s16x8*)(Bs + boff[n]);
    __syncthreads();
    if (ks < 15) {
      int off = (ks + 1) * 32;
      gll16(gA0 + off, lA0); gll16(gA1 + off, lA1);
      gll16(gB0 + off, lB0); gll16(gB1 + off, lB1);
    }
#pragma unroll
    for (int m = 0; m < 4; ++m)
#pragma unroll
      for (int n = 0; n < 4; ++n)
        acc[m][n] = __builtin_amdgcn_mfma_f32_16x16x32_bf16(af[m], bfr[n], acc[m][n], 0, 0, 0);
  }

  // epilogue: C/D layout col=lane&15, row=(lane>>4)*4+reg
#pragma unroll
  for (int m = 0; m < 4; ++m) {
    int rbase = wr * 64 + m * 16 + fq * 4;
    int tok[4]; float g[4];
#pragma unroll
    for (int j = 0; j < 4; ++j) { tok[j] = rowTok[rbase + j]; g[j] = rowG[rbase + j]; }
#pragma unroll
    for (int n = 0; n < 4; ++n) {
      int col = c0 + wc * 64 + n * 16 + fr;
#pragma unroll
      for (int j = 0; j < 4; ++j) {
        if (tok[j] >= 0)
          out[((long)b * NN + tok[j]) * OUTD + col] = acc[m][n][j] * g[j];
      }
    }
  }
}

extern "C" void kernel_launch(void* const* d_in, const int* in_sizes, int n_in,
                              void* d_out, int out_size, void* d_ws, size_t ws_size,
                              hipStream_t stream) {
  const float* x  = (const float*)d_in[0];
  const float* gw = (const float*)d_in[1];
  const float* ex = (const float*)d_in[2];
  float* out = (float*)d_out;

  char* wsb = (char*)d_ws;
  float*          t0     = (float*)(wsb);                          // 1 MiB
  unsigned short* xbf    = (unsigned short*)(wsb + (1l << 20));    // 32 MiB
  unsigned short* WT     = (unsigned short*)(wsb + (33l << 20));   // 4 MiB
  const long base = 37l << 20;
  float*          R      = (float*)(wsb + base);                           // 128 KiB
  int*            eo     = (int*)  (wsb + base + (128l << 10));            // 128 KiB
  int*            lists  = (int*)  (wsb + base + (256l << 10));            // 128 KiB
  float*          gvals  = (float*)(wsb + base + (384l << 10));            // 128 KiB
  float*          C      = (float*)(wsb + base + (512l << 10));            // 32 B
  int*            counts = (int*)  (wsb + base + (512l << 10) + 1024);     // 128 B
  float*          pm     = (float*)(wsb + base + (512l << 10) + 2048);     // 2 KiB
  float*          ps     = (float*)(wsb + base + (512l << 10) + 2048 + 2048); // 2 KiB
  int*            scnt   = (int*)  (wsb + base + (512l << 10) + 2048 + 4096); // 128 B

  hipMemsetAsync(eo, 0xFF, (size_t)BB * NN * 4, stream);
  hipMemsetAsync(counts, 0, (size_t)BB * EE * 4, stream);
  hipMemsetAsync(scnt, 0, (size_t)ITERS * BB * 4, stream);

  k_gate<<<(BB * NN) / 4, 256, 0, stream>>>(x, gw, t0, xbf);
  k_wt<<<dim3(OUTD / 32, DD / 32, EE), 256, 0, stream>>>(ex, WT);
  k_sink3<<<BB * SB, 1024, 0, stream>>>(t0, R, C, pm, ps, scnt);
  k_topk<<<BB * EE, 1024, 0, stream>>>(t0, R, eo);
  k_build<<<(BB * NN) / 256, 256, 0, stream>>>(eo, t0, R, C, counts, lists, gvals);
  k_zero<<<(BB * NN) / 4, 256, 0, stream>>>(eo, out);
  k_gemm<<<dim3(OUTD / 128, TOPM / 128, BB * EE), 256, 0, stream>>>(xbf, WT, counts, lists, gvals, out);
}

// Round 5
// 275.119 us; speedup vs baseline: 1.8235x; 1.0319x over previous
//
#include <hip/hip_runtime.h>
#include <hip/hip_bf16.h>

#define BB 4
#define NN 8192
#define DD 512
#define EE 8
#define OUTD 512
#define TOPM 1024
#define EPSV 1e-6f
#define ITERS 8
#define SB 8            // sinkhorn blocks per batch

using s16x8 = __attribute__((ext_vector_type(8))) short;
using f32x4 = __attribute__((ext_vector_type(4))) float;

__device__ __forceinline__ unsigned short f2bf(float f) {
  unsigned u = __float_as_uint(f);
  return (unsigned short)((u + 0x7FFFu + ((u >> 16) & 1u)) >> 16);
}

__device__ __forceinline__ void gll16(const void* g, void* l) {
  __builtin_amdgcn_global_load_lds((const __attribute__((address_space(1))) void*)g,
                                   (__attribute__((address_space(3))) void*)l, 16, 0, 0);
}

// ---- gate logits -> t0 = log(max(x@gw, eps)); x -> bf16; also init eo/counts/scnt ----
__global__ __launch_bounds__(256) void k_gate(const float* __restrict__ x,
                                              const float* __restrict__ gw,
                                              float* __restrict__ t0,
                                              unsigned short* __restrict__ xbf,
                                              int* __restrict__ eo,
                                              int* __restrict__ counts,
                                              int* __restrict__ scnt) {
  const int tid = threadIdx.x;
  if (blockIdx.x < 128) eo[blockIdx.x * 256 + tid] = -1;          // 32768 ints
  if (blockIdx.x == 128) {
    if (tid < BB * EE) counts[tid] = 0;
    else if (tid >= 64 && tid < 64 + ITERS * BB) scnt[tid - 64] = 0;
  }
  const int lane = tid & 63;
  const int wid  = tid >> 6;
  const long row = (long)blockIdx.x * 4 + wid;   // B*N rows, grid=8192
  const float* xr = x + row * DD + lane * 8;
  float4 xa = *(const float4*)(xr);
  float4 xb = *(const float4*)(xr + 4);
  float xv[8] = {xa.x, xa.y, xa.z, xa.w, xb.x, xb.y, xb.z, xb.w};

  s16x8 xo;
#pragma unroll
  for (int j = 0; j < 8; ++j) xo[j] = (short)f2bf(xv[j]);
  *(s16x8*)(xbf + row * DD + lane * 8) = xo;

  float acc[8] = {0.f,0.f,0.f,0.f,0.f,0.f,0.f,0.f};
  const float* gbase = gw + (lane * 8) * EE;
#pragma unroll
  for (int j = 0; j < 8; ++j) {
    float4 g0 = *(const float4*)(gbase + j * EE);
    float4 g1 = *(const float4*)(gbase + j * EE + 4);
    acc[0] += xv[j] * g0.x; acc[1] += xv[j] * g0.y;
    acc[2] += xv[j] * g0.z; acc[3] += xv[j] * g0.w;
    acc[4] += xv[j] * g1.x; acc[5] += xv[j] * g1.y;
    acc[6] += xv[j] * g1.z; acc[7] += xv[j] * g1.w;
  }
#pragma unroll
  for (int off = 32; off; off >>= 1) {
#pragma unroll
    for (int e = 0; e < 8; ++e) acc[e] += __shfl_xor(acc[e], off);
  }
  if (lane < 8) t0[row * EE + lane] = logf(fmaxf(acc[lane], EPSV));
}

// ---- fused Sinkhorn (blocks 0..31, relaxed-spin barrier) + expert transpose (blocks 32+) ----
__global__ __launch_bounds__(1024) void k_sink3(const float* __restrict__ t0,
                                                float* __restrict__ R,
                                                float* __restrict__ C,
                                                float* __restrict__ pm,   // [2][BB][SB][EE]
                                                float* __restrict__ ps,   // [2][BB][SB][EE]
                                                int* __restrict__ cnt,    // [ITERS][BB]
                                                const float* __restrict__ W,
                                                unsigned short* __restrict__ WT) {
  const int tid = threadIdx.x;         // 1024
  if (blockIdx.x >= BB * SB) {
    // ---- expert transpose path: f32 [e][k][n] -> bf16 [e][n][k], 64x64 tiles ----
    __shared__ float tl[64][65];
    const int widx = blockIdx.x - BB * SB;      // 0..511
    const int e = widx >> 6;
    const int rem = widx & 63;
    const int k0 = (rem >> 3) * 64, n0 = (rem & 7) * 64;
    const int ty = tid >> 6, tx = tid & 63;
    const float* src = W + ((long)e * DD + k0) * OUTD + n0;
#pragma unroll
    for (int j = 0; j < 4; ++j)
      tl[ty + j * 16][tx] = src[(long)(ty + j * 16) * OUTD + tx];
    __syncthreads();
    unsigned short* dst = WT + ((long)e * OUTD + n0) * DD + k0;
#pragma unroll
    for (int j = 0; j < 4; ++j)
      dst[(long)(ty + j * 16) * DD + tx] = f2bf(tl[tx][ty + j * 16]);
    return;
  }
  const int g = blockIdx.x;            // 32 = BB*SB
  const int b = g >> 3, s = g & 7;
  const int wv = tid >> 6, ln = tid & 63;
  const int n = s * 1024 + tid;
  const float* p = t0 + ((long)b * NN + n) * EE;
  float4 v0 = *(const float4*)p, v1 = *(const float4*)(p + 4);
  float tv[8] = {v0.x, v0.y, v0.z, v0.w, v1.x, v1.y, v1.z, v1.w};
  float r = 0.f;
  __shared__ float rm[16][8], rs[16][8], Csh[8];
  for (int it = 0; it < ITERS; ++it) {
    // block-local per-e (M,S) over this block's 1024 rows
#pragma unroll
    for (int e = 0; e < 8; ++e) {
      float v = tv[e] - r;
      float M = v;
#pragma unroll
      for (int o = 32; o; o >>= 1) M = fmaxf(M, __shfl_xor(M, o));
      float sv = expf(v - M);
#pragma unroll
      for (int o = 32; o; o >>= 1) sv += __shfl_xor(sv, o);
      if (ln == 0) { rm[wv][e] = M; rs[wv][e] = sv; }
    }
    __syncthreads();
    if (tid < 8) {
      float M = rm[0][tid], S = rs[0][tid];
#pragma unroll
      for (int q = 1; q < 16; ++q) {
        float mo = rm[q][tid], so = rs[q][tid];
        float Mx = fmaxf(M, mo);
        S = S * expf(M - Mx) + so * expf(mo - Mx);
        M = Mx;
      }
      const int idx = (((it & 1) * BB + b) * SB + s) * EE + tid;
      __hip_atomic_store(&pm[idx], M, __ATOMIC_RELAXED, __HIP_MEMORY_SCOPE_AGENT);
      __hip_atomic_store(&ps[idx], S, __ATOMIC_RELAXED, __HIP_MEMORY_SCOPE_AGENT);
    }
    __syncthreads();   // drains vmcnt: all 8 partial stores at the coherence point
    if (tid == 0) {
      int* ctr = &cnt[it * BB + b];
      __hip_atomic_fetch_add(ctr, 1, __ATOMIC_RELEASE, __HIP_MEMORY_SCOPE_AGENT);
      // RELAXED spin: no per-poll L2 invalidate (acquire-per-poll = invalidation storm)
      while (__hip_atomic_load(ctr, __ATOMIC_RELAXED, __HIP_MEMORY_SCOPE_AGENT) < SB)
        __builtin_amdgcn_s_sleep(1);
      (void)__hip_atomic_load(ctr, __ATOMIC_ACQUIRE, __HIP_MEMORY_SCOPE_AGENT);
    }
    __syncthreads();
    // combine this batch's SB partials (device-scope loads: per-XCD L2 non-coherent)
    if (tid < 8) {
      const float* qm = pm + ((it & 1) * BB + b) * SB * EE + tid;
      const float* qs = ps + ((it & 1) * BB + b) * SB * EE + tid;
      float M = __hip_atomic_load(&qm[0], __ATOMIC_RELAXED, __HIP_MEMORY_SCOPE_AGENT);
      float S = __hip_atomic_load(&qs[0], __ATOMIC_RELAXED, __HIP_MEMORY_SCOPE_AGENT);
#pragma unroll
      for (int q = 1; q < SB; ++q) {
        float mo = __hip_atomic_load(&qm[q * EE], __ATOMIC_RELAXED, __HIP_MEMORY_SCOPE_AGENT);
        float so = __hip_atomic_load(&qs[q * EE], __ATOMIC_RELAXED, __HIP_MEMORY_SCOPE_AGENT);
        float Mx = fmaxf(M, mo);
        S = S * expf(M - Mx) + so * expf(mo - Mx);
        M = Mx;
      }
      Csh[tid] = M + logf(S);
    }
    __syncthreads();
    float c8[8];
#pragma unroll
    for (int e2 = 0; e2 < 8; ++e2) c8[e2] = Csh[e2];
    // row step (register-local)
    float mx = tv[0] - c8[0];
#pragma unroll
    for (int e2 = 1; e2 < 8; ++e2) mx = fmaxf(mx, tv[e2] - c8[e2]);
    float ss = 0.f;
#pragma unroll
    for (int e2 = 0; e2 < 8; ++e2) ss += expf(tv[e2] - c8[e2] - mx);
    r = mx + logf(ss);
  }
  R[(long)b * NN + n] = r;
  if (s == 0 && tid < 8) C[b * EE + tid] = Csh[tid];
}

// ---------------- exact top-1024 per (b,e) column via radix select ----------------
__global__ __launch_bounds__(1024) void k_topk(const float* __restrict__ t0,
                                               const float* __restrict__ R,
                                               int* __restrict__ expert_of) {
  __shared__ unsigned key[NN];
  __shared__ int hist[256];
  __shared__ int bcast[2];
  __shared__ int wsum[16];
  const int b = blockIdx.x >> 3, e = blockIdx.x & 7;
  const int tid = threadIdx.x;
  const int wv = tid >> 6, ln = tid & 63;
  const float* t = t0 + (long)b * NN * EE + e;
  const float* Rb = R + b * NN;
  for (int n = tid; n < NN; n += 1024) {
    float f = t[n * EE] - Rb[n];
    unsigned u = __float_as_uint(f);
    u = (u & 0x80000000u) ? ~u : (u | 0x80000000u);   // sortable: larger u = larger f
    key[n] = u;
  }
  __syncthreads();
  unsigned prefix = 0, mask = 0;
  int k = TOPM;
  for (int shift = 24; shift >= 0; shift -= 8) {
    if (tid < 256) hist[tid] = 0;
    __syncthreads();
    for (int n = tid; n < NN; n += 1024) {
      unsigned u = key[n];
      if ((u & mask) == prefix) atomicAdd(&hist[(u >> shift) & 255], 1);
    }
    __syncthreads();
    // parallel suffix-sum over 256 bins (Hillis-Steele)
    for (int d = 1; d < 256; d <<= 1) {
      int add = 0;
      if (tid < 256 - d) add = hist[tid + d];
      __syncthreads();
      if (tid < 256) hist[tid] += add;
      __syncthreads();
    }
    if (tid < 256) {
      int sv = hist[tid];
      int sv1 = (tid < 255) ? hist[tid + 1] : 0;
      if (sv >= k && sv1 < k) { bcast[0] = k - sv1; bcast[1] = tid; }
    }
    __syncthreads();
    k = bcast[0];
    prefix |= ((unsigned)bcast[1]) << shift;
    mask |= (255u << shift);
    __syncthreads();
  }
  const unsigned theta = prefix;
  const int need = k;                  // ties (==theta) to take, lowest index first
  const int base = tid * 8;            // contiguous chunks -> deterministic index order
  int c = 0;
#pragma unroll
  for (int j = 0; j < 8; ++j) if (key[base + j] == theta) ++c;
  // wave-level inclusive scan of tie counts
  int inc = c;
#pragma unroll
  for (int d = 1; d < 64; d <<= 1) {
    int o = __shfl_up(inc, d);
    if (ln >= d) inc += o;
  }
  if (ln == 63) wsum[wv] = inc;
  __syncthreads();
  if (tid == 0) {
    int runv = 0;
    for (int i = 0; i < 16; ++i) { int t2 = wsum[i]; wsum[i] = runv; runv += t2; }
  }
  __syncthreads();
  int run = wsum[wv] + inc - c;        // exclusive prefix of this thread's ties
  int* eo = expert_of + b * NN;
  for (int j = 0; j < 8; ++j) {
    int n = base + j;
    unsigned u = key[n];
    bool sel = false;
    if (u > theta) sel = true;
    else if (u == theta) { if (run < need) sel = true; ++run; }
    if (sel) atomicMax(&eo[n], e);     // np scatter: largest expert index wins
  }
}

// ---------------- compact per-(b,e) token lists + gate values ----------------
__global__ __launch_bounds__(256) void k_build(const int* __restrict__ expert_of,
                                               const float* __restrict__ t0,
                                               const float* __restrict__ R,
                                               const float* __restrict__ C,
                                               int* __restrict__ counts,
                                               int* __restrict__ lists,
                                               float* __restrict__ gvals) {
  const long i = (long)blockIdx.x * 256 + threadIdx.x;
  const int e = expert_of[i];
  if (e < 0) return;
  const int b = (int)(i >> 13);
  const int n = (int)(i & (NN - 1));
  const int be = b * EE + e;
  const int pos = atomicAdd(&counts[be], 1);
  const int slot = be * TOPM + pos;
  lists[slot] = n;
  gvals[slot] = expf(t0[i * EE + e] - C[be] - R[i]);
}

// ---------------- zero output rows of unselected tokens ----------------
__global__ __launch_bounds__(256) void k_zero(const int* __restrict__ eo,
                                              float* __restrict__ out) {
  const int row = blockIdx.x * 4 + (threadIdx.x >> 6);
  if (eo[row] >= 0) return;
  const int ln = threadIdx.x & 63;
  float4 z = make_float4(0.f, 0.f, 0.f, 0.f);
  float4* p = (float4*)(out + (long)row * OUTD) + ln;
  p[0] = z; p[64] = z;
}

// ---------------- gathered bf16 MFMA GEMM: out[tok,:] = g * x[tok,:] @ W[e] ----------------
__global__ __launch_bounds__(256) void k_gemm(const unsigned short* __restrict__ xbf,
                                              const unsigned short* __restrict__ WT,
                                              const int* __restrict__ counts,
                                              const int* __restrict__ lists,
                                              const float* __restrict__ gvals,
                                              float* __restrict__ out) {
  const int be = blockIdx.z;
  const int b = be >> 3, e = be & 7;
  const int cnt = counts[be];
  const int r0 = blockIdx.y * 128;
  if (r0 >= cnt) return;
  const int c0 = blockIdx.x * 128;

  __shared__ unsigned short As[128 * 32];   // [row][k] bf16, k-slot XOR-swizzled
  __shared__ unsigned short Bs[128 * 32];   // [col][k] bf16 (from WT), same swizzle
  __shared__ int   rowTok[128];
  __shared__ float rowG[128];

  const int tid = threadIdx.x;
  if (tid < 128) {
    int r = r0 + tid;
    rowTok[tid] = (r < cnt) ? lists[be * TOPM + r] : -1;
    rowG[tid]   = (r < cnt) ? gvals[be * TOPM + r] : 0.f;
  }
  __syncthreads();

  const int w = tid >> 6, l = tid & 63;
  const int c_a = 2 * w, c_b = 2 * w + 1;
  const int rr = l >> 2;
  const int slot = l & 3;
  const int ra0 = c_a * 16 + rr;
  const int ra1 = c_b * 16 + rr;
  const int kg0 = slot ^ ((ra0 >> 1) & 3);   // pre-swizzled global k-chunk (involution)
  const int kg1 = slot ^ ((ra1 >> 1) & 3);
  int tA0 = rowTok[ra0]; if (tA0 < 0) tA0 = 0;
  int tA1 = rowTok[ra1]; if (tA1 < 0) tA1 = 0;
  const unsigned short* gA0 = xbf + ((long)b * NN + tA0) * DD + kg0 * 8;
  const unsigned short* gA1 = xbf + ((long)b * NN + tA1) * DD + kg1 * 8;
  const unsigned short* gB0 = WT + ((long)e * OUTD + c0 + ra0) * DD + kg0 * 8;
  const unsigned short* gB1 = WT + ((long)e * OUTD + c0 + ra1) * DD + kg1 * 8;
  unsigned short* lA0 = As + c_a * 512;
  unsigned short* lA1 = As + c_b * 512;
  unsigned short* lB0 = Bs + c_a * 512;
  unsigned short* lB1 = Bs + c_b * 512;

  const int wr = w >> 1, wc = w & 1;
  const int fr = l & 15, fq = l >> 4;
  int aoff[4], boff[4];
#pragma unroll
  for (int m = 0; m < 4; ++m) {
    int row = wr * 64 + m * 16 + fr;
    aoff[m] = row * 32 + (fq ^ ((row >> 1) & 3)) * 8;   // swizzled read matches staged layout
    int col = wc * 64 + m * 16 + fr;
    boff[m] = col * 32 + (fq ^ ((col >> 1) & 3)) * 8;
  }

  f32x4 acc[4][4] = {};

  gll16(gA0, lA0); gll16(gA1, lA1);
  gll16(gB0, lB0); gll16(gB1, lB1);

  for (int ks = 0; ks < 16; ++ks) {
    __syncthreads();
    s16x8 af[4], bfr[4];
#pragma unroll
    for (int m = 0; m < 4; ++m) af[m] = *(const s16x8*)(As + aoff[m]);
#pragma unroll
    for (int n = 0; n < 4; ++n) bfr[n] = *(const s16x8*)(Bs + boff[n]);
    __syncthreads();
    if (ks < 15) {
      int off = (ks + 1) * 32;
      gll16(gA0 + off, lA0); gll16(gA1 + off, lA1);
      gll16(gB0 + off, lB0); gll16(gB1 + off, lB1);
    }
#pragma unroll
    for (int m = 0; m < 4; ++m)
#pragma unroll
      for (int n = 0; n < 4; ++n)
        acc[m][n] = __builtin_amdgcn_mfma_f32_16x16x32_bf16(af[m], bfr[n], acc[m][n], 0, 0, 0);
  }

  // epilogue: C/D layout col=lane&15, row=(lane>>4)*4+reg
#pragma unroll
  for (int m = 0; m < 4; ++m) {
    int rbase = wr * 64 + m * 16 + fq * 4;
    int tok[4]; float g[4];
#pragma unroll
    for (int j = 0; j < 4; ++j) { tok[j] = rowTok[rbase + j]; g[j] = rowG[rbase + j]; }
#pragma unroll
    for (int n = 0; n < 4; ++n) {
      int col = c0 + wc * 64 + n * 16 + fr;
#pragma unroll
      for (int j = 0; j < 4; ++j) {
        if (tok[j] >= 0)
          out[((long)b * NN + tok[j]) * OUTD + col] = acc[m][n][j] * g[j];
      }
    }
  }
}

extern "C" void kernel_launch(void* const* d_in, const int* in_sizes, int n_in,
                              void* d_out, int out_size, void* d_ws, size_t ws_size,
                              hipStream_t stream) {
  const float* x  = (const float*)d_in[0];
  const float* gw = (const float*)d_in[1];
  const float* ex = (const float*)d_in[2];
  float* out = (float*)d_out;

  char* wsb = (char*)d_ws;
  float*          t0     = (float*)(wsb);                          // 1 MiB
  unsigned short* xbf    = (unsigned short*)(wsb + (1l << 20));    // 32 MiB
  unsigned short* WT     = (unsigned short*)(wsb + (33l << 20));   // 4 MiB
  const long base = 37l << 20;
  float*          R      = (float*)(wsb + base);                           // 128 KiB
  int*            eo     = (int*)  (wsb + base + (128l << 10));            // 128 KiB
  int*            lists  = (int*)  (wsb + base + (256l << 10));            // 128 KiB
  float*          gvals  = (float*)(wsb + base + (384l << 10));            // 128 KiB
  float*          C      = (float*)(wsb + base + (512l << 10));            // 32 B
  int*            counts = (int*)  (wsb + base + (512l << 10) + 1024);     // 128 B
  float*          pm     = (float*)(wsb + base + (512l << 10) + 2048);     // 2 KiB
  float*          ps     = (float*)(wsb + base + (512l << 10) + 2048 + 2048); // 2 KiB
  int*            scnt   = (int*)  (wsb + base + (512l << 10) + 2048 + 4096); // 128 B

  k_gate<<<(BB * NN) / 4, 256, 0, stream>>>(x, gw, t0, xbf, eo, counts, scnt);
  k_sink3<<<BB * SB + 512, 1024, 0, stream>>>(t0, R, C, pm, ps, scnt, ex, WT);
  k_topk<<<BB * EE, 1024, 0, stream>>>(t0, R, eo);
  k_build<<<(BB * NN) / 256, 256, 0, stream>>>(eo, t0, R, C, counts, lists, gvals);
  k_zero<<<(BB * NN) / 4, 256, 0, stream>>>(eo, out);
  k_gemm<<<dim3(OUTD / 128, TOPM / 128, BB * EE), 256, 0, stream>>>(xbf, WT, counts, lists, gvals, out);
}

// Round 6
// 243.441 us; speedup vs baseline: 2.0608x; 1.1301x over previous
//
#include <hip/hip_runtime.h>
#include <hip/hip_bf16.h>

#define BB 4
#define NN 8192
#define DD 512
#define EE 8
#define OUTD 512
#define TOPM 1024
#define EPSV 1e-6f
#define ITERS 8
#define SB 8            // sinkhorn blocks per batch

using s16x8 = __attribute__((ext_vector_type(8))) short;
using f32x4 = __attribute__((ext_vector_type(4))) float;
typedef unsigned long long u64;

__device__ __forceinline__ unsigned short f2bf(float f) {
  unsigned u = __float_as_uint(f);
  return (unsigned short)((u + 0x7FFFu + ((u >> 16) & 1u)) >> 16);
}

__device__ __forceinline__ void gll16(const void* g, void* l) {
  __builtin_amdgcn_global_load_lds((const __attribute__((address_space(1))) void*)g,
                                   (__attribute__((address_space(3))) void*)l, 16, 0, 0);
}

// ---- gate logits -> t0 = log(max(x@gw, eps)); x -> bf16; expert transpose;
// ---- also init eo / counts / pq sentinels (harness poisons ws with 0xAA) ----
__global__ __launch_bounds__(256) void k_gate(const float* __restrict__ x,
                                              const float* __restrict__ gw,
                                              float* __restrict__ t0,
                                              unsigned short* __restrict__ xbf,
                                              int* __restrict__ eo,
                                              int* __restrict__ counts,
                                              u64* __restrict__ pq,
                                              const float* __restrict__ W,
                                              unsigned short* __restrict__ WT) {
  const int tid = threadIdx.x;
  if (blockIdx.x >= 8192) {
    // ---- expert transpose: f32 [e][k][n] -> bf16 [e][n][k], 32x32 tiles ----
    __shared__ float tl[32][33];
    const int widx = blockIdx.x - 8192;          // 0..2047
    const int e = widx >> 8, rem = widx & 255;
    const int k0 = (rem >> 4) * 32, n0 = (rem & 15) * 32;
    const int ty = tid >> 5, tx = tid & 31;
    const float* src = W + ((long)e * DD + k0) * OUTD + n0;
#pragma unroll
    for (int j = 0; j < 4; ++j)
      tl[ty + j * 8][tx] = src[(long)(ty + j * 8) * OUTD + tx];
    __syncthreads();
    unsigned short* dst = WT + ((long)e * OUTD + n0) * DD + k0;
#pragma unroll
    for (int j = 0; j < 4; ++j)
      dst[(long)(ty + j * 8) * DD + tx] = f2bf(tl[tx][ty + j * 8]);
    return;
  }
  if (blockIdx.x < 128) eo[blockIdx.x * 256 + tid] = -1;          // 32768 ints
  if (blockIdx.x == 128 && tid < BB * EE) counts[tid] = 0;
  if (blockIdx.x == 129) {                                        // sentinel-init pq
#pragma unroll
    for (int j = 0; j < 8; ++j) pq[tid * 8 + j] = ~0ull;          // 2048 u64
  }
  const int lane = tid & 63;
  const int wid  = tid >> 6;
  const long row = (long)blockIdx.x * 4 + wid;   // B*N rows
  const float* xr = x + row * DD + lane * 8;
  float4 xa = *(const float4*)(xr);
  float4 xb = *(const float4*)(xr + 4);
  float xv[8] = {xa.x, xa.y, xa.z, xa.w, xb.x, xb.y, xb.z, xb.w};

  s16x8 xo;
#pragma unroll
  for (int j = 0; j < 8; ++j) xo[j] = (short)f2bf(xv[j]);
  *(s16x8*)(xbf + row * DD + lane * 8) = xo;

  float acc[8] = {0.f,0.f,0.f,0.f,0.f,0.f,0.f,0.f};
  const float* gbase = gw + (lane * 8) * EE;
#pragma unroll
  for (int j = 0; j < 8; ++j) {
    float4 g0 = *(const float4*)(gbase + j * EE);
    float4 g1 = *(const float4*)(gbase + j * EE + 4);
    acc[0] += xv[j] * g0.x; acc[1] += xv[j] * g0.y;
    acc[2] += xv[j] * g0.z; acc[3] += xv[j] * g0.w;
    acc[4] += xv[j] * g1.x; acc[5] += xv[j] * g1.y;
    acc[6] += xv[j] * g1.z; acc[7] += xv[j] * g1.w;
  }
#pragma unroll
  for (int off = 32; off; off >>= 1) {
#pragma unroll
    for (int e = 0; e < 8; ++e) acc[e] += __shfl_xor(acc[e], off);
  }
  if (lane < 8) t0[row * EE + lane] = logf(fmaxf(acc[lane], EPSV));
}

// ---- fused Sinkhorn: 32 blocks, 1 row/thread, sentinel-word barrier (no RMW, no fence) ----
__global__ __launch_bounds__(1024) void k_sink4(const float* __restrict__ t0,
                                                float* __restrict__ R,
                                                float* __restrict__ C,
                                                u64* __restrict__ pq) { // [ITERS][BB][SB][EE]
  const int g = blockIdx.x;            // 32 = BB*SB
  const int b = g >> 3, s = g & 7;
  const int tid = threadIdx.x;         // 1024
  const int wv = tid >> 6, ln = tid & 63;
  const int n = s * 1024 + tid;
  const float* p = t0 + ((long)b * NN + n) * EE;
  float4 v0 = *(const float4*)p, v1 = *(const float4*)(p + 4);
  float tv[8] = {v0.x, v0.y, v0.z, v0.w, v1.x, v1.y, v1.z, v1.w};
  float r = 0.f;
  __shared__ float rm[16][8], rs[16][8], Csh[8];
  for (int it = 0; it < ITERS; ++it) {
    // block-local per-e (M,S) over this block's 1024 rows
#pragma unroll
    for (int e = 0; e < 8; ++e) {
      float v = tv[e] - r;
      float M = v;
#pragma unroll
      for (int o = 32; o; o >>= 1) M = fmaxf(M, __shfl_xor(M, o));
      float sv = expf(v - M);
#pragma unroll
      for (int o = 32; o; o >>= 1) sv += __shfl_xor(sv, o);
      if (ln == 0) { rm[wv][e] = M; rs[wv][e] = sv; }
    }
    __syncthreads();
    if (tid < 64) {
      // wave 0: combine 16 wave-partials -> block partial (lane l: wavepair l>>3, e=l&7)
      const int q = tid >> 3, e = tid & 7;
      float M = rm[q][e], S = rs[q][e];
      float mo = rm[q + 8][e], so = rs[q + 8][e];
      float Mx = fmaxf(M, mo); S = S * expf(M - Mx) + so * expf(mo - Mx); M = Mx;
#pragma unroll
      for (int d = 8; d < 64; d <<= 1) {
        mo = __shfl_xor(M, d); so = __shfl_xor(S, d);
        Mx = fmaxf(M, mo); S = S * expf(M - Mx) + so * expf(mo - Mx); M = Mx;
      }
      u64* bp = pq + (long)(it * BB + b) * (SB * EE);
      if (tid < 8) {
        // data word IS the sync token: M in low 32, S in high 32 (M never 0xFFFFFFFF)
        u64 pk = ((u64)__float_as_uint(S) << 32) | (u64)__float_as_uint(M);
        __hip_atomic_store(&bp[s * EE + tid], pk, __ATOMIC_RELAXED, __HIP_MEMORY_SCOPE_AGENT);
      }
      // poll all 64 slot-words (8 slots x 8 e) with one coalesced wave load
      u64 v;
      for (;;) {
        v = __hip_atomic_load(&bp[tid], __ATOMIC_RELAXED, __HIP_MEMORY_SCOPE_AGENT);
        if (!__ballot((unsigned)v == 0xFFFFFFFFu)) break;
        __builtin_amdgcn_s_sleep(1);
      }
      float M2 = __uint_as_float((unsigned)v);
      float S2 = __uint_as_float((unsigned)(v >> 32));
#pragma unroll
      for (int d = 8; d < 64; d <<= 1) {   // combine across the 8 slots (fixed tree)
        float mo2 = __shfl_xor(M2, d), so2 = __shfl_xor(S2, d);
        float Mx2 = fmaxf(M2, mo2);
        S2 = S2 * expf(M2 - Mx2) + so2 * expf(mo2 - Mx2);
        M2 = Mx2;
      }
      if (tid < 8) Csh[tid] = M2 + logf(S2);
    }
    __syncthreads();
    float c8[8];
#pragma unroll
    for (int e2 = 0; e2 < 8; ++e2) c8[e2] = Csh[e2];
    // row step (register-local)
    float mx = tv[0] - c8[0];
#pragma unroll
    for (int e2 = 1; e2 < 8; ++e2) mx = fmaxf(mx, tv[e2] - c8[e2]);
    float ss = 0.f;
#pragma unroll
    for (int e2 = 0; e2 < 8; ++e2) ss += expf(tv[e2] - c8[e2] - mx);
    r = mx + logf(ss);
    __syncthreads();
  }
  R[(long)b * NN + n] = r;
  if (s == 0 && tid < 8) C[b * EE + tid] = Csh[tid];
}

// ---------------- exact top-1024 per (b,e) column via radix select ----------------
__global__ __launch_bounds__(1024) void k_topk(const float* __restrict__ t0,
                                               const float* __restrict__ R,
                                               int* __restrict__ expert_of) {
  __shared__ unsigned key[NN];
  __shared__ int hist[256];
  __shared__ int bcast[2];
  __shared__ int wsum[16];
  const int b = blockIdx.x >> 3, e = blockIdx.x & 7;
  const int tid = threadIdx.x;
  const int wv = tid >> 6, ln = tid & 63;
  const float* t = t0 + (long)b * NN * EE + e;
  const float* Rb = R + b * NN;
  for (int n = tid; n < NN; n += 1024) {
    float f = t[n * EE] - Rb[n];
    unsigned u = __float_as_uint(f);
    u = (u & 0x80000000u) ? ~u : (u | 0x80000000u);   // sortable: larger u = larger f
    key[n] = u;
  }
  __syncthreads();
  unsigned prefix = 0, mask = 0;
  int k = TOPM;
  for (int shift = 24; shift >= 0; shift -= 8) {
    if (tid < 256) hist[tid] = 0;
    __syncthreads();
    for (int n = tid; n < NN; n += 1024) {
      unsigned u = key[n];
      if ((u & mask) == prefix) atomicAdd(&hist[(u >> shift) & 255], 1);
    }
    __syncthreads();
    // parallel suffix-sum over 256 bins (Hillis-Steele)
    for (int d = 1; d < 256; d <<= 1) {
      int add = 0;
      if (tid < 256 - d) add = hist[tid + d];
      __syncthreads();
      if (tid < 256) hist[tid] += add;
      __syncthreads();
    }
    if (tid < 256) {
      int sv = hist[tid];
      int sv1 = (tid < 255) ? hist[tid + 1] : 0;
      if (sv >= k && sv1 < k) { bcast[0] = k - sv1; bcast[1] = tid; }
    }
    __syncthreads();
    k = bcast[0];
    prefix |= ((unsigned)bcast[1]) << shift;
    mask |= (255u << shift);
    __syncthreads();
  }
  const unsigned theta = prefix;
  const int need = k;                  // ties (==theta) to take, lowest index first
  const int base = tid * 8;            // contiguous chunks -> deterministic index order
  int c = 0;
#pragma unroll
  for (int j = 0; j < 8; ++j) if (key[base + j] == theta) ++c;
  // wave-level inclusive scan of tie counts
  int inc = c;
#pragma unroll
  for (int d = 1; d < 64; d <<= 1) {
    int o = __shfl_up(inc, d);
    if (ln >= d) inc += o;
  }
  if (ln == 63) wsum[wv] = inc;
  __syncthreads();
  if (tid == 0) {
    int runv = 0;
    for (int i = 0; i < 16; ++i) { int t2 = wsum[i]; wsum[i] = runv; runv += t2; }
  }
  __syncthreads();
  int run = wsum[wv] + inc - c;        // exclusive prefix of this thread's ties
  int* eo = expert_of + b * NN;
  for (int j = 0; j < 8; ++j) {
    int n = base + j;
    unsigned u = key[n];
    bool sel = false;
    if (u > theta) sel = true;
    else if (u == theta) { if (run < need) sel = true; ++run; }
    if (sel) atomicMax(&eo[n], e);     // np scatter: largest expert index wins
  }
}

// ---------------- compact per-(b,e) token lists + gate values ----------------
__global__ __launch_bounds__(256) void k_build(const int* __restrict__ expert_of,
                                               const float* __restrict__ t0,
                                               const float* __restrict__ R,
                                               const float* __restrict__ C,
                                               int* __restrict__ counts,
                                               int* __restrict__ lists,
                                               float* __restrict__ gvals) {
  const long i = (long)blockIdx.x * 256 + threadIdx.x;
  const int e = expert_of[i];
  if (e < 0) return;
  const int b = (int)(i >> 13);
  const int n = (int)(i & (NN - 1));
  const int be = b * EE + e;
  const int pos = atomicAdd(&counts[be], 1);
  const int slot = be * TOPM + pos;
  lists[slot] = n;
  gvals[slot] = expf(t0[i * EE + e] - C[be] - R[i]);
}

// ---------------- zero output rows of unselected tokens ----------------
__global__ __launch_bounds__(256) void k_zero(const int* __restrict__ eo,
                                              float* __restrict__ out) {
  const int row = blockIdx.x * 4 + (threadIdx.x >> 6);
  if (eo[row] >= 0) return;
  const int ln = threadIdx.x & 63;
  float4 z = make_float4(0.f, 0.f, 0.f, 0.f);
  float4* p = (float4*)(out + (long)row * OUTD) + ln;
  p[0] = z; p[64] = z;
}

// ---------------- gathered bf16 MFMA GEMM: out[tok,:] = g * x[tok,:] @ W[e] ----------------
__global__ __launch_bounds__(256) void k_gemm(const unsigned short* __restrict__ xbf,
                                              const unsigned short* __restrict__ WT,
                                              const int* __restrict__ counts,
                                              const int* __restrict__ lists,
                                              const float* __restrict__ gvals,
                                              float* __restrict__ out) {
  const int be = blockIdx.z;
  const int b = be >> 3, e = be & 7;
  const int cnt = counts[be];
  const int r0 = blockIdx.y * 128;
  if (r0 >= cnt) return;
  const int c0 = blockIdx.x * 128;

  __shared__ unsigned short As[128 * 32];   // [row][k] bf16, k-slot XOR-swizzled
  __shared__ unsigned short Bs[128 * 32];   // [col][k] bf16 (from WT), same swizzle
  __shared__ int   rowTok[128];
  __shared__ float rowG[128];

  const int tid = threadIdx.x;
  if (tid < 128) {
    int r = r0 + tid;
    rowTok[tid] = (r < cnt) ? lists[be * TOPM + r] : -1;
    rowG[tid]   = (r < cnt) ? gvals[be * TOPM + r] : 0.f;
  }
  __syncthreads();

  const int w = tid >> 6, l = tid & 63;
  const int c_a = 2 * w, c_b = 2 * w + 1;
  const int rr = l >> 2;
  const int slot = l & 3;
  const int ra0 = c_a * 16 + rr;
  const int ra1 = c_b * 16 + rr;
  const int kg0 = slot ^ ((ra0 >> 1) & 3);   // pre-swizzled global k-chunk (involution)
  const int kg1 = slot ^ ((ra1 >> 1) & 3);
  int tA0 = rowTok[ra0]; if (tA0 < 0) tA0 = 0;
  int tA1 = rowTok[ra1]; if (tA1 < 0) tA1 = 0;
  const unsigned short* gA0 = xbf + ((long)b * NN + tA0) * DD + kg0 * 8;
  const unsigned short* gA1 = xbf + ((long)b * NN + tA1) * DD + kg1 * 8;
  const unsigned short* gB0 = WT + ((long)e * OUTD + c0 + ra0) * DD + kg0 * 8;
  const unsigned short* gB1 = WT + ((long)e * OUTD + c0 + ra1) * DD + kg1 * 8;
  unsigned short* lA0 = As + c_a * 512;
  unsigned short* lA1 = As + c_b * 512;
  unsigned short* lB0 = Bs + c_a * 512;
  unsigned short* lB1 = Bs + c_b * 512;

  const int wr = w >> 1, wc = w & 1;
  const int fr = l & 15, fq = l >> 4;
  int aoff[4], boff[4];
#pragma unroll
  for (int m = 0; m < 4; ++m) {
    int row = wr * 64 + m * 16 + fr;
    aoff[m] = row * 32 + (fq ^ ((row >> 1) & 3)) * 8;   // swizzled read matches staged layout
    int col = wc * 64 + m * 16 + fr;
    boff[m] = col * 32 + (fq ^ ((col >> 1) & 3)) * 8;
  }

  f32x4 acc[4][4] = {};

  gll16(gA0, lA0); gll16(gA1, lA1);
  gll16(gB0, lB0); gll16(gB1, lB1);

  for (int ks = 0; ks < 16; ++ks) {
    __syncthreads();
    s16x8 af[4], bfr[4];
#pragma unroll
    for (int m = 0; m < 4; ++m) af[m] = *(const s16x8*)(As + aoff[m]);
#pragma unroll
    for (int n = 0; n < 4; ++n) bfr[n] = *(const s16x8*)(Bs + boff[n]);
    __syncthreads();
    if (ks < 15) {
      int off = (ks + 1) * 32;
      gll16(gA0 + off, lA0); gll16(gA1 + off, lA1);
      gll16(gB0 + off, lB0); gll16(gB1 + off, lB1);
    }
#pragma unroll
    for (int m = 0; m < 4; ++m)
#pragma unroll
      for (int n = 0; n < 4; ++n)
        acc[m][n] = __builtin_amdgcn_mfma_f32_16x16x32_bf16(af[m], bfr[n], acc[m][n], 0, 0, 0);
  }

  // epilogue: C/D layout col=lane&15, row=(lane>>4)*4+reg
#pragma unroll
  for (int m = 0; m < 4; ++m) {
    int rbase = wr * 64 + m * 16 + fq * 4;
    int tok[4]; float g[4];
#pragma unroll
    for (int j = 0; j < 4; ++j) { tok[j] = rowTok[rbase + j]; g[j] = rowG[rbase + j]; }
#pragma unroll
    for (int n = 0; n < 4; ++n) {
      int col = c0 + wc * 64 + n * 16 + fr;
#pragma unroll
      for (int j = 0; j < 4; ++j) {
        if (tok[j] >= 0)
          out[((long)b * NN + tok[j]) * OUTD + col] = acc[m][n][j] * g[j];
      }
    }
  }
}

extern "C" void kernel_launch(void* const* d_in, const int* in_sizes, int n_in,
                              void* d_out, int out_size, void* d_ws, size_t ws_size,
                              hipStream_t stream) {
  const float* x  = (const float*)d_in[0];
  const float* gw = (const float*)d_in[1];
  const float* ex = (const float*)d_in[2];
  float* out = (float*)d_out;

  char* wsb = (char*)d_ws;
  float*          t0     = (float*)(wsb);                          // 1 MiB
  unsigned short* xbf    = (unsigned short*)(wsb + (1l << 20));    // 32 MiB
  unsigned short* WT     = (unsigned short*)(wsb + (33l << 20));   // 4 MiB
  const long base = 37l << 20;
  float*          R      = (float*)(wsb + base);                           // 128 KiB
  int*            eo     = (int*)  (wsb + base + (128l << 10));            // 128 KiB
  int*            lists  = (int*)  (wsb + base + (256l << 10));            // 128 KiB
  float*          gvals  = (float*)(wsb + base + (384l << 10));            // 128 KiB
  float*          C      = (float*)(wsb + base + (512l << 10));            // 32 B
  int*            counts = (int*)  (wsb + base + (512l << 10) + 1024);     // 128 B
  u64*            pq     = (u64*)  (wsb + base + (512l << 10) + 2048);     // 16 KiB

  k_gate<<<8192 + 2048, 256, 0, stream>>>(x, gw, t0, xbf, eo, counts, pq, ex, WT);
  k_sink4<<<BB * SB, 1024, 0, stream>>>(t0, R, C, pq);
  k_topk<<<BB * EE, 1024, 0, stream>>>(t0, R, eo);
  k_build<<<(BB * NN) / 256, 256, 0, stream>>>(eo, t0, R, C, counts, lists, gvals);
  k_zero<<<(BB * NN) / 4, 256, 0, stream>>>(eo, out);
  k_gemm<<<dim3(OUTD / 128, TOPM / 128, BB * EE), 256, 0, stream>>>(xbf, WT, counts, lists, gvals, out);
}

// Round 7
// 207.221 us; speedup vs baseline: 2.4210x; 1.1748x over previous
//
#include <hip/hip_runtime.h>
#include <hip/hip_bf16.h>

#define BB 4
#define NN 8192
#define DD 512
#define EE 8
#define OUTD 512
#define TOPM 1024
#define EPSV 1e-6f
#define ITERS 8
#define SB 8            // sinkhorn blocks per batch

using s16x8 = __attribute__((ext_vector_type(8))) short;
using f32x4 = __attribute__((ext_vector_type(4))) float;
typedef unsigned long long u64;

__device__ __forceinline__ unsigned short f2bf(float f) {
  unsigned u = __float_as_uint(f);
  return (unsigned short)((u + 0x7FFFu + ((u >> 16) & 1u)) >> 16);
}

__device__ __forceinline__ void gll16(const void* g, void* l) {
  __builtin_amdgcn_global_load_lds((const __attribute__((address_space(1))) void*)g,
                                   (__attribute__((address_space(3))) void*)l, 16, 0, 0);
}

// ---- gate logits -> t0 = log(max(x@gw, eps)); x -> bf16; expert transpose;
// ---- gw hoisted to VGPRs (8 rows/wave); init eo/counts/pq ----
__global__ __launch_bounds__(256) void k_gate(const float* __restrict__ x,
                                              const float* __restrict__ gw,
                                              float* __restrict__ t0,
                                              unsigned short* __restrict__ xbf,
                                              int* __restrict__ eo,
                                              int* __restrict__ counts,
                                              u64* __restrict__ pq,
                                              const float* __restrict__ W,
                                              unsigned short* __restrict__ WT) {
  const int tid = threadIdx.x;
  if (blockIdx.x >= 1024) {
    // ---- expert transpose: f32 [e][k][n] -> bf16 [e][n][k], 32x32 tiles ----
    __shared__ float tl[32][33];
    const int widx = blockIdx.x - 1024;          // 0..2047
    const int e = widx >> 8, rem = widx & 255;
    const int k0 = (rem >> 4) * 32, n0 = (rem & 15) * 32;
    const int ty = tid >> 5, tx = tid & 31;
    const float* src = W + ((long)e * DD + k0) * OUTD + n0;
#pragma unroll
    for (int j = 0; j < 4; ++j)
      tl[ty + j * 8][tx] = src[(long)(ty + j * 8) * OUTD + tx];
    __syncthreads();
    unsigned short* dst = WT + ((long)e * OUTD + n0) * DD + k0;
#pragma unroll
    for (int j = 0; j < 4; ++j)
      dst[(long)(ty + j * 8) * DD + tx] = f2bf(tl[tx][ty + j * 8]);
    return;
  }
  if (tid < 32) eo[blockIdx.x * 32 + tid] = -1;                   // 1024*32 = 32768
  if (blockIdx.x == 0 && tid >= 64 && tid < 64 + BB * EE) counts[tid - 64] = 0;
  if (blockIdx.x == 1) {                                          // sentinel-init pq
#pragma unroll
    for (int j = 0; j < 8; ++j) pq[tid * 8 + j] = ~0ull;          // 2048 u64
  }
  const int lane = tid & 63;
  const int w    = tid >> 6;
  // hoist gw into regs: lane covers k in [lane*8, lane*8+8)
  float4 g0[8], g1[8];
  const float* gb = gw + (lane * 8) * EE;
#pragma unroll
  for (int q = 0; q < 8; ++q) {
    g0[q] = *(const float4*)(gb + q * EE);
    g1[q] = *(const float4*)(gb + q * EE + 4);
  }
  const long row0 = (long)blockIdx.x * 32 + w * 8;
  for (int i = 0; i < 8; ++i) {
    const long row = row0 + i;
    const float* xr = x + row * DD + lane * 8;
    float4 xa = *(const float4*)(xr);
    float4 xb = *(const float4*)(xr + 4);
    float xv[8] = {xa.x, xa.y, xa.z, xa.w, xb.x, xb.y, xb.z, xb.w};
    s16x8 xo;
#pragma unroll
    for (int j = 0; j < 8; ++j) xo[j] = (short)f2bf(xv[j]);
    *(s16x8*)(xbf + row * DD + lane * 8) = xo;

    float acc[8] = {0.f,0.f,0.f,0.f,0.f,0.f,0.f,0.f};
#pragma unroll
    for (int q = 0; q < 8; ++q) {
      acc[0] += xv[q] * g0[q].x; acc[1] += xv[q] * g0[q].y;
      acc[2] += xv[q] * g0[q].z; acc[3] += xv[q] * g0[q].w;
      acc[4] += xv[q] * g1[q].x; acc[5] += xv[q] * g1[q].y;
      acc[6] += xv[q] * g1[q].z; acc[7] += xv[q] * g1[q].w;
    }
    // masked butterfly: levels 1,2,4 fold 8 accs toward e = lane&7
#pragma unroll
    for (int d = 1; d <= 4; d <<= 1) {
#pragma unroll
      for (int e = 0; e < 8; ++e) {
        float tmp = __shfl_xor(acc[e], d);
        acc[e] += ((lane & d) == (e & d)) ? tmp : 0.f;
      }
    }
    float v = acc[0];
#pragma unroll
    for (int e = 1; e < 8; ++e) v = ((lane & 7) == e) ? acc[e] : v;
#pragma unroll
    for (int d = 8; d < 64; d <<= 1) v += __shfl_xor(v, d);
    if (lane < 8) t0[row * EE + lane] = logf(fmaxf(v, EPSV));
  }
}

// ---- fused Sinkhorn: 32 blocks, 1 row/thread, sentinel-word barrier (no RMW, no fence) ----
__global__ __launch_bounds__(1024) void k_sink4(const float* __restrict__ t0,
                                                float* __restrict__ R,
                                                float* __restrict__ C,
                                                u64* __restrict__ pq) { // [ITERS][BB][SB][EE]
  const int g = blockIdx.x;            // 32 = BB*SB
  const int b = g >> 3, s = g & 7;
  const int tid = threadIdx.x;         // 1024
  const int wv = tid >> 6, ln = tid & 63;
  const int n = s * 1024 + tid;
  const float* p = t0 + ((long)b * NN + n) * EE;
  float4 v0 = *(const float4*)p, v1 = *(const float4*)(p + 4);
  float tv[8] = {v0.x, v0.y, v0.z, v0.w, v1.x, v1.y, v1.z, v1.w};
  float r = 0.f;
  __shared__ float rm[16][8], rs[16][8], Csh[8];
  for (int it = 0; it < ITERS; ++it) {
#pragma unroll
    for (int e = 0; e < 8; ++e) {
      float v = tv[e] - r;
      float M = v;
#pragma unroll
      for (int o = 32; o; o >>= 1) M = fmaxf(M, __shfl_xor(M, o));
      float sv = expf(v - M);
#pragma unroll
      for (int o = 32; o; o >>= 1) sv += __shfl_xor(sv, o);
      if (ln == 0) { rm[wv][e] = M; rs[wv][e] = sv; }
    }
    __syncthreads();
    if (tid < 64) {
      const int q = tid >> 3, e = tid & 7;
      float M = rm[q][e], S = rs[q][e];
      float mo = rm[q + 8][e], so = rs[q + 8][e];
      float Mx = fmaxf(M, mo); S = S * expf(M - Mx) + so * expf(mo - Mx); M = Mx;
#pragma unroll
      for (int d = 8; d < 64; d <<= 1) {
        mo = __shfl_xor(M, d); so = __shfl_xor(S, d);
        Mx = fmaxf(M, mo); S = S * expf(M - Mx) + so * expf(mo - Mx); M = Mx;
      }
      u64* bp = pq + (long)(it * BB + b) * (SB * EE);
      if (tid < 8) {
        u64 pk = ((u64)__float_as_uint(S) << 32) | (u64)__float_as_uint(M);
        __hip_atomic_store(&bp[s * EE + tid], pk, __ATOMIC_RELAXED, __HIP_MEMORY_SCOPE_AGENT);
      }
      u64 v;
      for (;;) {
        v = __hip_atomic_load(&bp[tid], __ATOMIC_RELAXED, __HIP_MEMORY_SCOPE_AGENT);
        if (!__ballot((unsigned)v == 0xFFFFFFFFu)) break;
        __builtin_amdgcn_s_sleep(1);
      }
      float M2 = __uint_as_float((unsigned)v);
      float S2 = __uint_as_float((unsigned)(v >> 32));
#pragma unroll
      for (int d = 8; d < 64; d <<= 1) {
        float mo2 = __shfl_xor(M2, d), so2 = __shfl_xor(S2, d);
        float Mx2 = fmaxf(M2, mo2);
        S2 = S2 * expf(M2 - Mx2) + so2 * expf(mo2 - Mx2);
        M2 = Mx2;
      }
      if (tid < 8) Csh[tid] = M2 + logf(S2);
    }
    __syncthreads();
    float c8[8];
#pragma unroll
    for (int e2 = 0; e2 < 8; ++e2) c8[e2] = Csh[e2];
    float mx = tv[0] - c8[0];
#pragma unroll
    for (int e2 = 1; e2 < 8; ++e2) mx = fmaxf(mx, tv[e2] - c8[e2]);
    float ss = 0.f;
#pragma unroll
    for (int e2 = 0; e2 < 8; ++e2) ss += expf(tv[e2] - c8[e2] - mx);
    r = mx + logf(ss);
    __syncthreads();
  }
  R[(long)b * NN + n] = r;
  if (s == 0 && tid < 8) C[b * EE + tid] = Csh[tid];
}

// ---------------- exact top-1024 per (b,e) column via radix select ----------------
__global__ __launch_bounds__(1024) void k_topk(const float* __restrict__ t0,
                                               const float* __restrict__ R,
                                               int* __restrict__ expert_of) {
  __shared__ unsigned key[NN];
  __shared__ int hist[256];
  __shared__ int bcast[2];
  __shared__ int wsum[16];
  const int b = blockIdx.x >> 3, e = blockIdx.x & 7;
  const int tid = threadIdx.x;
  const int wv = tid >> 6, ln = tid & 63;
  const float* t = t0 + (long)b * NN * EE + e;
  const float* Rb = R + b * NN;
  for (int n = tid; n < NN; n += 1024) {
    float f = t[n * EE] - Rb[n];
    unsigned u = __float_as_uint(f);
    u = (u & 0x80000000u) ? ~u : (u | 0x80000000u);   // sortable: larger u = larger f
    key[n] = u;
  }
  __syncthreads();
  unsigned prefix = 0, mask = 0;
  int k = TOPM;
  for (int shift = 24; shift >= 0; shift -= 8) {
    if (tid < 256) hist[tid] = 0;
    __syncthreads();
    for (int n = tid; n < NN; n += 1024) {
      unsigned u = key[n];
      if ((u & mask) == prefix) atomicAdd(&hist[(u >> shift) & 255], 1);
    }
    __syncthreads();
    for (int d = 1; d < 256; d <<= 1) {
      int add = 0;
      if (tid < 256 - d) add = hist[tid + d];
      __syncthreads();
      if (tid < 256) hist[tid] += add;
      __syncthreads();
    }
    if (tid < 256) {
      int sv = hist[tid];
      int sv1 = (tid < 255) ? hist[tid + 1] : 0;
      if (sv >= k && sv1 < k) { bcast[0] = k - sv1; bcast[1] = tid; }
    }
    __syncthreads();
    k = bcast[0];
    prefix |= ((unsigned)bcast[1]) << shift;
    mask |= (255u << shift);
    __syncthreads();
  }
  const unsigned theta = prefix;
  const int need = k;
  const int base = tid * 8;
  int c = 0;
#pragma unroll
  for (int j = 0; j < 8; ++j) if (key[base + j] == theta) ++c;
  int inc = c;
#pragma unroll
  for (int d = 1; d < 64; d <<= 1) {
    int o = __shfl_up(inc, d);
    if (ln >= d) inc += o;
  }
  if (ln == 63) wsum[wv] = inc;
  __syncthreads();
  if (tid == 0) {
    int runv = 0;
    for (int i = 0; i < 16; ++i) { int t2 = wsum[i]; wsum[i] = runv; runv += t2; }
  }
  __syncthreads();
  int run = wsum[wv] + inc - c;
  int* eo = expert_of + b * NN;
  for (int j = 0; j < 8; ++j) {
    int n = base + j;
    unsigned u = key[n];
    bool sel = false;
    if (u > theta) sel = true;
    else if (u == theta) { if (run < need) sel = true; ++run; }
    if (sel) atomicMax(&eo[n], e);     // np scatter: largest expert index wins
  }
}

// ---------------- compact per-(b,e) token lists + gate values ----------------
__global__ __launch_bounds__(256) void k_build(const int* __restrict__ expert_of,
                                               const float* __restrict__ t0,
                                               const float* __restrict__ R,
                                               const float* __restrict__ C,
                                               int* __restrict__ counts,
                                               int* __restrict__ lists,
                                               float* __restrict__ gvals) {
  const long i = (long)blockIdx.x * 256 + threadIdx.x;
  const int e = expert_of[i];
  if (e < 0) return;
  const int b = (int)(i >> 13);
  const int n = (int)(i & (NN - 1));
  const int be = b * EE + e;
  const int pos = atomicAdd(&counts[be], 1);
  const int slot = be * TOPM + pos;
  lists[slot] = n;
  gvals[slot] = expf(t0[i * EE + e] - C[be] - R[i]);
}

// ---------------- zero output rows of unselected tokens ----------------
__global__ __launch_bounds__(256) void k_zero(const int* __restrict__ eo,
                                              float* __restrict__ out) {
  const int row = blockIdx.x * 4 + (threadIdx.x >> 6);
  if (eo[row] >= 0) return;
  const int ln = threadIdx.x & 63;
  float4 z = make_float4(0.f, 0.f, 0.f, 0.f);
  float4* p = (float4*)(out + (long)row * OUTD) + ln;
  p[0] = z; p[64] = z;
}

// ---------------- gathered bf16 MFMA GEMM: out[tok,:] = g * x[tok,:] @ W[e] ----------------
__global__ __launch_bounds__(256) void k_gemm(const unsigned short* __restrict__ xbf,
                                              const unsigned short* __restrict__ WT,
                                              const int* __restrict__ counts,
                                              const int* __restrict__ lists,
                                              const float* __restrict__ gvals,
                                              float* __restrict__ out) {
  const int be = blockIdx.z;
  const int b = be >> 3, e = be & 7;
  const int cnt = counts[be];
  const int r0 = blockIdx.y * 128;
  if (r0 >= cnt) return;
  const int c0 = blockIdx.x * 128;

  __shared__ unsigned short As[128 * 32];   // [row][k] bf16, k-slot XOR-swizzled
  __shared__ unsigned short Bs[128 * 32];   // [col][k] bf16 (from WT), same swizzle
  __shared__ int   rowTok[128];
  __shared__ float rowG[128];

  const int tid = threadIdx.x;
  if (tid < 128) {
    int r = r0 + tid;
    rowTok[tid] = (r < cnt) ? lists[be * TOPM + r] : -1;
    rowG[tid]   = (r < cnt) ? gvals[be * TOPM + r] : 0.f;
  }
  __syncthreads();

  const int w = tid >> 6, l = tid & 63;
  const int c_a = 2 * w, c_b = 2 * w + 1;
  const int rr = l >> 2;
  const int slot = l & 3;
  const int ra0 = c_a * 16 + rr;
  const int ra1 = c_b * 16 + rr;
  const int kg0 = slot ^ ((ra0 >> 1) & 3);   // pre-swizzled global k-chunk (involution)
  const int kg1 = slot ^ ((ra1 >> 1) & 3);
  int tA0 = rowTok[ra0]; if (tA0 < 0) tA0 = 0;
  int tA1 = rowTok[ra1]; if (tA1 < 0) tA1 = 0;
  const unsigned short* gA0 = xbf + ((long)b * NN + tA0) * DD + kg0 * 8;
  const unsigned short* gA1 = xbf + ((long)b * NN + tA1) * DD + kg1 * 8;
  const unsigned short* gB0 = WT + ((long)e * OUTD + c0 + ra0) * DD + kg0 * 8;
  const unsigned short* gB1 = WT + ((long)e * OUTD + c0 + ra1) * DD + kg1 * 8;
  unsigned short* lA0 = As + c_a * 512;
  unsigned short* lA1 = As + c_b * 512;
  unsigned short* lB0 = Bs + c_a * 512;
  unsigned short* lB1 = Bs + c_b * 512;

  const int wr = w >> 1, wc = w & 1;
  const int fr = l & 15, fq = l >> 4;
  int aoff[4], boff[4];
#pragma unroll
  for (int m = 0; m < 4; ++m) {
    int row = wr * 64 + m * 16 + fr;
    aoff[m] = row * 32 + (fq ^ ((row >> 1) & 3)) * 8;   // swizzled read matches staged layout
    int col = wc * 64 + m * 16 + fr;
    boff[m] = col * 32 + (fq ^ ((col >> 1) & 3)) * 8;
  }

  f32x4 acc[4][4] = {};

  gll16(gA0, lA0); gll16(gA1, lA1);
  gll16(gB0, lB0); gll16(gB1, lB1);

  for (int ks = 0; ks < 16; ++ks) {
    __syncthreads();
    s16x8 af[4], bfr[4];
#pragma unroll
    for (int m = 0; m < 4; ++m) af[m] = *(const s16x8*)(As + aoff[m]);
#pragma unroll
    for (int n = 0; n < 4; ++n) bfr[n] = *(const s16x8*)(Bs + boff[n]);
    __syncthreads();
    if (ks < 15) {
      int off = (ks + 1) * 32;
      gll16(gA0 + off, lA0); gll16(gA1 + off, lA1);
      gll16(gB0 + off, lB0); gll16(gB1 + off, lB1);
    }
#pragma unroll
    for (int m = 0; m < 4; ++m)
#pragma unroll
      for (int n = 0; n < 4; ++n)
        acc[m][n] = __builtin_amdgcn_mfma_f32_16x16x32_bf16(af[m], bfr[n], acc[m][n], 0, 0, 0);
  }

  // epilogue: C/D layout col=lane&15, row=(lane>>4)*4+reg
#pragma unroll
  for (int m = 0; m < 4; ++m) {
    int rbase = wr * 64 + m * 16 + fq * 4;
    int tok[4]; float g[4];
#pragma unroll
    for (int j = 0; j < 4; ++j) { tok[j] = rowTok[rbase + j]; g[j] = rowG[rbase + j]; }
#pragma unroll
    for (int n = 0; n < 4; ++n) {
      int col = c0 + wc * 64 + n * 16 + fr;
#pragma unroll
      for (int j = 0; j < 4; ++j) {
        if (tok[j] >= 0)
          out[((long)b * NN + tok[j]) * OUTD + col] = acc[m][n][j] * g[j];
      }
    }
  }
}

extern "C" void kernel_launch(void* const* d_in, const int* in_sizes, int n_in,
                              void* d_out, int out_size, void* d_ws, size_t ws_size,
                              hipStream_t stream) {
  const float* x  = (const float*)d_in[0];
  const float* gw = (const float*)d_in[1];
  const float* ex = (const float*)d_in[2];
  float* out = (float*)d_out;

  char* wsb = (char*)d_ws;
  float*          t0     = (float*)(wsb);                          // 1 MiB
  unsigned short* xbf    = (unsigned short*)(wsb + (1l << 20));    // 32 MiB
  unsigned short* WT     = (unsigned short*)(wsb + (33l << 20));   // 4 MiB
  const long base = 37l << 20;
  float*          R      = (float*)(wsb + base);                           // 128 KiB
  int*            eo     = (int*)  (wsb + base + (128l << 10));            // 128 KiB
  int*            lists  = (int*)  (wsb + base + (256l << 10));            // 128 KiB
  float*          gvals  = (float*)(wsb + base + (384l << 10));            // 128 KiB
  float*          C      = (float*)(wsb + base + (512l << 10));            // 32 B
  int*            counts = (int*)  (wsb + base + (512l << 10) + 1024);     // 128 B
  u64*            pq     = (u64*)  (wsb + base + (512l << 10) + 2048);     // 16 KiB

  k_gate<<<1024 + 2048, 256, 0, stream>>>(x, gw, t0, xbf, eo, counts, pq, ex, WT);
  k_sink4<<<BB * SB, 1024, 0, stream>>>(t0, R, C, pq);
  k_topk<<<BB * EE, 1024, 0, stream>>>(t0, R, eo);
  k_build<<<(BB * NN) / 256, 256, 0, stream>>>(eo, t0, R, C, counts, lists, gvals);
  k_zero<<<(BB * NN) / 4, 256, 0, stream>>>(eo, out);
  k_gemm<<<dim3(OUTD / 128, TOPM / 128, BB * EE), 256, 0, stream>>>(xbf, WT, counts, lists, gvals, out);
}

// Round 8
// 175.785 us; speedup vs baseline: 2.8539x; 1.1788x over previous
//
#include <hip/hip_runtime.h>
#include <hip/hip_bf16.h>

#define BB 4
#define NN 8192
#define DD 512
#define EE 8
#define OUTD 512
#define TOPM 1024
#define EPSV 1e-6f
#define ITERS 8

using s16x8 = __attribute__((ext_vector_type(8))) short;
using f32x4 = __attribute__((ext_vector_type(4))) float;
typedef unsigned long long u64;

__device__ __forceinline__ unsigned short f2bf(float f) {
  unsigned u = __float_as_uint(f);
  return (unsigned short)((u + 0x7FFFu + ((u >> 16) & 1u)) >> 16);
}

__device__ __forceinline__ void gll16(const void* g, void* l) {
  __builtin_amdgcn_global_load_lds((const __attribute__((address_space(1))) void*)g,
                                   (__attribute__((address_space(3))) void*)l, 16, 0, 0);
}

// ---- gate logits -> t0 = log(max(x@gw, eps)); x -> bf16; expert transpose;
// ---- gw hoisted to VGPRs (8 rows/wave); init eo/counts ----
__global__ __launch_bounds__(256) void k_gate(const float* __restrict__ x,
                                              const float* __restrict__ gw,
                                              float* __restrict__ t0,
                                              unsigned short* __restrict__ xbf,
                                              int* __restrict__ eo,
                                              int* __restrict__ counts,
                                              const float* __restrict__ W,
                                              unsigned short* __restrict__ WT) {
  const int tid = threadIdx.x;
  if (blockIdx.x >= 1024) {
    // ---- expert transpose: f32 [e][k][n] -> bf16 [e][n][k], 32x32 tiles ----
    __shared__ float tl[32][33];
    const int widx = blockIdx.x - 1024;          // 0..2047
    const int e = widx >> 8, rem = widx & 255;
    const int k0 = (rem >> 4) * 32, n0 = (rem & 15) * 32;
    const int ty = tid >> 5, tx = tid & 31;
    const float* src = W + ((long)e * DD + k0) * OUTD + n0;
#pragma unroll
    for (int j = 0; j < 4; ++j)
      tl[ty + j * 8][tx] = src[(long)(ty + j * 8) * OUTD + tx];
    __syncthreads();
    unsigned short* dst = WT + ((long)e * OUTD + n0) * DD + k0;
#pragma unroll
    for (int j = 0; j < 4; ++j)
      dst[(long)(ty + j * 8) * DD + tx] = f2bf(tl[tx][ty + j * 8]);
    return;
  }
  if (tid < 32) eo[blockIdx.x * 32 + tid] = -1;                   // 1024*32 = 32768
  if (blockIdx.x == 0 && tid >= 64 && tid < 64 + BB * EE) counts[tid - 64] = 0;
  const int lane = tid & 63;
  const int w    = tid >> 6;
  float4 g0[8], g1[8];
  const float* gb = gw + (lane * 8) * EE;
#pragma unroll
  for (int q = 0; q < 8; ++q) {
    g0[q] = *(const float4*)(gb + q * EE);
    g1[q] = *(const float4*)(gb + q * EE + 4);
  }
  const long row0 = (long)blockIdx.x * 32 + w * 8;
  for (int i = 0; i < 8; ++i) {
    const long row = row0 + i;
    const float* xr = x + row * DD + lane * 8;
    float4 xa = *(const float4*)(xr);
    float4 xb = *(const float4*)(xr + 4);
    float xv[8] = {xa.x, xa.y, xa.z, xa.w, xb.x, xb.y, xb.z, xb.w};
    s16x8 xo;
#pragma unroll
    for (int j = 0; j < 8; ++j) xo[j] = (short)f2bf(xv[j]);
    *(s16x8*)(xbf + row * DD + lane * 8) = xo;

    float acc[8] = {0.f,0.f,0.f,0.f,0.f,0.f,0.f,0.f};
#pragma unroll
    for (int q = 0; q < 8; ++q) {
      acc[0] += xv[q] * g0[q].x; acc[1] += xv[q] * g0[q].y;
      acc[2] += xv[q] * g0[q].z; acc[3] += xv[q] * g0[q].w;
      acc[4] += xv[q] * g1[q].x; acc[5] += xv[q] * g1[q].y;
      acc[6] += xv[q] * g1[q].z; acc[7] += xv[q] * g1[q].w;
    }
#pragma unroll
    for (int d = 1; d <= 4; d <<= 1) {
#pragma unroll
      for (int e = 0; e < 8; ++e) {
        float tmp = __shfl_xor(acc[e], d);
        acc[e] += ((lane & d) == (e & d)) ? tmp : 0.f;
      }
    }
    float v = acc[0];
#pragma unroll
    for (int e = 1; e < 8; ++e) v = ((lane & 7) == e) ? acc[e] : v;
#pragma unroll
    for (int d = 8; d < 64; d <<= 1) v += __shfl_xor(v, d);
    if (lane < 8) t0[row * EE + lane] = logf(fmaxf(v, EPSV));
  }
}

// ---- linear-domain fused Sinkhorn: 1 block/batch, 8 rows/thread, NO global sync ----
// E = exp(t0) (= clipped logit); u = exp(-R); v = exp(-C).
// col: S[e] = sum_n E*u, v = 1/S ; row: D[n] = sum_e E*v, u = 1/D.
__global__ __launch_bounds__(1024) void k_sink5(const float* __restrict__ t0,
                                                float* __restrict__ R,
                                                float* __restrict__ C) {
  const int b = blockIdx.x;            // 4 blocks
  const int tid = threadIdx.x;         // 1024
  const int wv = tid >> 6, ln = tid & 63;
  const float* tb = t0 + (long)b * NN * EE;
  float E[8][8], u[8], dl[8];
  __shared__ float ws[16][8];
  __shared__ float Csh[8];
  __shared__ float Ssh[8];
#pragma unroll
  for (int j = 0; j < 8; ++j) {
    const float* p = tb + (long)(j * 1024 + tid) * EE;
    float4 a = *(const float4*)p, b4 = *(const float4*)(p + 4);
    E[j][0] = expf(a.x);  E[j][1] = expf(a.y);
    E[j][2] = expf(a.z);  E[j][3] = expf(a.w);
    E[j][4] = expf(b4.x); E[j][5] = expf(b4.y);
    E[j][6] = expf(b4.z); E[j][7] = expf(b4.w);
    u[j] = 1.f;
  }
  for (int it = 0; it < ITERS; ++it) {
    // ---- col step: per-thread partial P[e] = sum_j E[j][e]*u[j] ----
    float P[8] = {0.f,0.f,0.f,0.f,0.f,0.f,0.f,0.f};
#pragma unroll
    for (int j = 0; j < 8; ++j)
#pragma unroll
      for (int e = 0; e < 8; ++e) P[e] += E[j][e] * u[j];
    // masked butterfly fold: levels 1,2,4 fold 8 accs toward e = lane&7
#pragma unroll
    for (int d = 1; d <= 4; d <<= 1) {
#pragma unroll
      for (int e = 0; e < 8; ++e) {
        float tmp = __shfl_xor(P[e], d);
        P[e] += ((ln & d) == (e & d)) ? tmp : 0.f;
      }
    }
    float pv = P[0];
#pragma unroll
    for (int e = 1; e < 8; ++e) pv = ((ln & 7) == e) ? P[e] : pv;
#pragma unroll
    for (int d = 8; d < 64; d <<= 1) pv += __shfl_xor(pv, d);
    if (ln < 8) ws[wv][ln] = pv;
    __syncthreads();
    if (tid < 64) {
      const int q = ln >> 3, e = ln & 7;
      float s = ws[q][e] + ws[q + 8][e];
#pragma unroll
      for (int d = 8; d < 64; d <<= 1) s += __shfl_xor(s, d);
      if (ln < 8) { Csh[ln] = 1.f / s; Ssh[ln] = s; }
    }
    __syncthreads();
    float vv[8];
#pragma unroll
    for (int e = 0; e < 8; ++e) vv[e] = Csh[e];
    // ---- row step: D = sum_e E*v, u = 1/D ----
#pragma unroll
    for (int j = 0; j < 8; ++j) {
      float d0 = E[j][0] * vv[0];
#pragma unroll
      for (int e = 1; e < 8; ++e) d0 += E[j][e] * vv[e];
      dl[j] = d0;
      u[j] = 1.f / d0;
    }
    __syncthreads();   // protect ws/Csh WAR before next iteration's writes
  }
#pragma unroll
  for (int j = 0; j < 8; ++j) R[(long)b * NN + j * 1024 + tid] = logf(dl[j]);
  if (tid < 8) C[b * EE + tid] = logf(Ssh[tid]);
}

// ---------------- exact top-1024 per (b,e) column via radix select ----------------
__global__ __launch_bounds__(1024) void k_topk(const float* __restrict__ t0,
                                               const float* __restrict__ R,
                                               int* __restrict__ expert_of) {
  __shared__ unsigned key[NN];
  __shared__ int hist[256];
  __shared__ int bcast[2];
  __shared__ int wsum[16];
  const int b = blockIdx.x >> 3, e = blockIdx.x & 7;
  const int tid = threadIdx.x;
  const int wv = tid >> 6, ln = tid & 63;
  const float* t = t0 + (long)b * NN * EE + e;
  const float* Rb = R + b * NN;
  for (int n = tid; n < NN; n += 1024) {
    float f = t[n * EE] - Rb[n];
    unsigned u = __float_as_uint(f);
    u = (u & 0x80000000u) ? ~u : (u | 0x80000000u);   // sortable: larger u = larger f
    key[n] = u;
  }
  __syncthreads();
  unsigned prefix = 0, mask = 0;
  int k = TOPM;
  for (int shift = 24; shift >= 0; shift -= 8) {
    if (tid < 256) hist[tid] = 0;
    __syncthreads();
    for (int n = tid; n < NN; n += 1024) {
      unsigned u = key[n];
      if ((u & mask) == prefix) atomicAdd(&hist[(u >> shift) & 255], 1);
    }
    __syncthreads();
    for (int d = 1; d < 256; d <<= 1) {
      int add = 0;
      if (tid < 256 - d) add = hist[tid + d];
      __syncthreads();
      if (tid < 256) hist[tid] += add;
      __syncthreads();
    }
    if (tid < 256) {
      int sv = hist[tid];
      int sv1 = (tid < 255) ? hist[tid + 1] : 0;
      if (sv >= k && sv1 < k) { bcast[0] = k - sv1; bcast[1] = tid; }
    }
    __syncthreads();
    k = bcast[0];
    prefix |= ((unsigned)bcast[1]) << shift;
    mask |= (255u << shift);
    __syncthreads();
  }
  const unsigned theta = prefix;
  const int need = k;
  const int base = tid * 8;
  int c = 0;
#pragma unroll
  for (int j = 0; j < 8; ++j) if (key[base + j] == theta) ++c;
  int inc = c;
#pragma unroll
  for (int d = 1; d < 64; d <<= 1) {
    int o = __shfl_up(inc, d);
    if (ln >= d) inc += o;
  }
  if (ln == 63) wsum[wv] = inc;
  __syncthreads();
  if (tid == 0) {
    int runv = 0;
    for (int i = 0; i < 16; ++i) { int t2 = wsum[i]; wsum[i] = runv; runv += t2; }
  }
  __syncthreads();
  int run = wsum[wv] + inc - c;
  int* eo = expert_of + b * NN;
  for (int j = 0; j < 8; ++j) {
    int n = base + j;
    unsigned u = key[n];
    bool sel = false;
    if (u > theta) sel = true;
    else if (u == theta) { if (run < need) sel = true; ++run; }
    if (sel) atomicMax(&eo[n], e);     // np scatter: largest expert index wins
  }
}

// ---------------- compact per-(b,e) token lists + gate values ----------------
__global__ __launch_bounds__(256) void k_build(const int* __restrict__ expert_of,
                                               const float* __restrict__ t0,
                                               const float* __restrict__ R,
                                               const float* __restrict__ C,
                                               int* __restrict__ counts,
                                               int* __restrict__ lists,
                                               float* __restrict__ gvals) {
  const long i = (long)blockIdx.x * 256 + threadIdx.x;
  const int e = expert_of[i];
  if (e < 0) return;
  const int b = (int)(i >> 13);
  const int n = (int)(i & (NN - 1));
  const int be = b * EE + e;
  const int pos = atomicAdd(&counts[be], 1);
  const int slot = be * TOPM + pos;
  lists[slot] = n;
  gvals[slot] = expf(t0[i * EE + e] - C[be] - R[i]);
}

// ---------------- zero output rows of unselected tokens ----------------
__global__ __launch_bounds__(256) void k_zero(const int* __restrict__ eo,
                                              float* __restrict__ out) {
  const int row = blockIdx.x * 4 + (threadIdx.x >> 6);
  if (eo[row] >= 0) return;
  const int ln = threadIdx.x & 63;
  float4 z = make_float4(0.f, 0.f, 0.f, 0.f);
  float4* p = (float4*)(out + (long)row * OUTD) + ln;
  p[0] = z; p[64] = z;
}

// ---------------- gathered bf16 MFMA GEMM: out[tok,:] = g * x[tok,:] @ W[e] ----------------
__global__ __launch_bounds__(256) void k_gemm(const unsigned short* __restrict__ xbf,
                                              const unsigned short* __restrict__ WT,
                                              const int* __restrict__ counts,
                                              const int* __restrict__ lists,
                                              const float* __restrict__ gvals,
                                              float* __restrict__ out) {
  const int be = blockIdx.z;
  const int b = be >> 3, e = be & 7;
  const int cnt = counts[be];
  const int r0 = blockIdx.y * 128;
  if (r0 >= cnt) return;
  const int c0 = blockIdx.x * 128;

  __shared__ unsigned short As[128 * 32];   // [row][k] bf16, k-slot XOR-swizzled
  __shared__ unsigned short Bs[128 * 32];   // [col][k] bf16 (from WT), same swizzle
  __shared__ int   rowTok[128];
  __shared__ float rowG[128];

  const int tid = threadIdx.x;
  if (tid < 128) {
    int r = r0 + tid;
    rowTok[tid] = (r < cnt) ? lists[be * TOPM + r] : -1;
    rowG[tid]   = (r < cnt) ? gvals[be * TOPM + r] : 0.f;
  }
  __syncthreads();

  const int w = tid >> 6, l = tid & 63;
  const int c_a = 2 * w, c_b = 2 * w + 1;
  const int rr = l >> 2;
  const int slot = l & 3;
  const int ra0 = c_a * 16 + rr;
  const int ra1 = c_b * 16 + rr;
  const int kg0 = slot ^ ((ra0 >> 1) & 3);   // pre-swizzled global k-chunk (involution)
  const int kg1 = slot ^ ((ra1 >> 1) & 3);
  int tA0 = rowTok[ra0]; if (tA0 < 0) tA0 = 0;
  int tA1 = rowTok[ra1]; if (tA1 < 0) tA1 = 0;
  const unsigned short* gA0 = xbf + ((long)b * NN + tA0) * DD + kg0 * 8;
  const unsigned short* gA1 = xbf + ((long)b * NN + tA1) * DD + kg1 * 8;
  const unsigned short* gB0 = WT + ((long)e * OUTD + c0 + ra0) * DD + kg0 * 8;
  const unsigned short* gB1 = WT + ((long)e * OUTD + c0 + ra1) * DD + kg1 * 8;
  unsigned short* lA0 = As + c_a * 512;
  unsigned short* lA1 = As + c_b * 512;
  unsigned short* lB0 = Bs + c_a * 512;
  unsigned short* lB1 = Bs + c_b * 512;

  const int wr = w >> 1, wc = w & 1;
  const int fr = l & 15, fq = l >> 4;
  int aoff[4], boff[4];
#pragma unroll
  for (int m = 0; m < 4; ++m) {
    int row = wr * 64 + m * 16 + fr;
    aoff[m] = row * 32 + (fq ^ ((row >> 1) & 3)) * 8;   // swizzled read matches staged layout
    int col = wc * 64 + m * 16 + fr;
    boff[m] = col * 32 + (fq ^ ((col >> 1) & 3)) * 8;
  }

  f32x4 acc[4][4] = {};

  gll16(gA0, lA0); gll16(gA1, lA1);
  gll16(gB0, lB0); gll16(gB1, lB1);

  for (int ks = 0; ks < 16; ++ks) {
    __syncthreads();
    s16x8 af[4], bfr[4];
#pragma unroll
    for (int m = 0; m < 4; ++m) af[m] = *(const s16x8*)(As + aoff[m]);
#pragma unroll
    for (int n = 0; n < 4; ++n) bfr[n] = *(const s16x8*)(Bs + boff[n]);
    __syncthreads();
    if (ks < 15) {
      int off = (ks + 1) * 32;
      gll16(gA0 + off, lA0); gll16(gA1 + off, lA1);
      gll16(gB0 + off, lB0); gll16(gB1 + off, lB1);
    }
#pragma unroll
    for (int m = 0; m < 4; ++m)
#pragma unroll
      for (int n = 0; n < 4; ++n)
        acc[m][n] = __builtin_amdgcn_mfma_f32_16x16x32_bf16(af[m], bfr[n], acc[m][n], 0, 0, 0);
  }

  // epilogue: C/D layout col=lane&15, row=(lane>>4)*4+reg
#pragma unroll
  for (int m = 0; m < 4; ++m) {
    int rbase = wr * 64 + m * 16 + fq * 4;
    int tok[4]; float g[4];
#pragma unroll
    for (int j = 0; j < 4; ++j) { tok[j] = rowTok[rbase + j]; g[j] = rowG[rbase + j]; }
#pragma unroll
    for (int n = 0; n < 4; ++n) {
      int col = c0 + wc * 64 + n * 16 + fr;
#pragma unroll
      for (int j = 0; j < 4; ++j) {
        if (tok[j] >= 0)
          out[((long)b * NN + tok[j]) * OUTD + col] = acc[m][n][j] * g[j];
      }
    }
  }
}

extern "C" void kernel_launch(void* const* d_in, const int* in_sizes, int n_in,
                              void* d_out, int out_size, void* d_ws, size_t ws_size,
                              hipStream_t stream) {
  const float* x  = (const float*)d_in[0];
  const float* gw = (const float*)d_in[1];
  const float* ex = (const float*)d_in[2];
  float* out = (float*)d_out;

  char* wsb = (char*)d_ws;
  float*          t0     = (float*)(wsb);                          // 1 MiB
  unsigned short* xbf    = (unsigned short*)(wsb + (1l << 20));    // 32 MiB
  unsigned short* WT     = (unsigned short*)(wsb + (33l << 20));   // 4 MiB
  const long base = 37l << 20;
  float*          R      = (float*)(wsb + base);                           // 128 KiB
  int*            eo     = (int*)  (wsb + base + (128l << 10));            // 128 KiB
  int*            lists  = (int*)  (wsb + base + (256l << 10));            // 128 KiB
  float*          gvals  = (float*)(wsb + base + (384l << 10));            // 128 KiB
  float*          C      = (float*)(wsb + base + (512l << 10));            // 32 B
  int*            counts = (int*)  (wsb + base + (512l << 10) + 1024);     // 128 B

  k_gate<<<1024 + 2048, 256, 0, stream>>>(x, gw, t0, xbf, eo, counts, ex, WT);
  k_sink5<<<BB, 1024, 0, stream>>>(t0, R, C);
  k_topk<<<BB * EE, 1024, 0, stream>>>(t0, R, eo);
  k_build<<<(BB * NN) / 256, 256, 0, stream>>>(eo, t0, R, C, counts, lists, gvals);
  k_zero<<<(BB * NN) / 4, 256, 0, stream>>>(eo, out);
  k_gemm<<<dim3(OUTD / 128, TOPM / 128, BB * EE), 256, 0, stream>>>(xbf, WT, counts, lists, gvals, out);
}

// Round 9
// 123.460 us; speedup vs baseline: 4.0635x; 1.4238x over previous
//
#include <hip/hip_runtime.h>
#include <hip/hip_bf16.h>

#define BB 4
#define NN 8192
#define DD 512
#define EE 8
#define OUTD 512
#define TOPM 1024
#define EPSV 1e-6f
#define ITERS 8

using s16x8 = __attribute__((ext_vector_type(8))) short;
using f32x4 = __attribute__((ext_vector_type(4))) float;
typedef unsigned long long u64;

__device__ __forceinline__ unsigned short f2bf(float f) {
  unsigned u = __float_as_uint(f);
  return (unsigned short)((u + 0x7FFFu + ((u >> 16) & 1u)) >> 16);
}

__device__ __forceinline__ void gll16(const void* g, void* l) {
  __builtin_amdgcn_global_load_lds((const __attribute__((address_space(1))) void*)g,
                                   (__attribute__((address_space(3))) void*)l, 16, 0, 0);
}

// ---- gate logits -> t0 = log(max(x@gw, eps)); x -> bf16; expert transpose;
// ---- gw hoisted to VGPRs (8 rows/wave); init eo/counts ----
__global__ __launch_bounds__(256) void k_gate(const float* __restrict__ x,
                                              const float* __restrict__ gw,
                                              float* __restrict__ t0,
                                              unsigned short* __restrict__ xbf,
                                              int* __restrict__ eo,
                                              int* __restrict__ counts,
                                              const float* __restrict__ W,
                                              unsigned short* __restrict__ WT) {
  const int tid = threadIdx.x;
  if (blockIdx.x >= 1024) {
    // ---- expert transpose: f32 [e][k][n] -> bf16 [e][n][k], 32x32 tiles ----
    __shared__ float tl[32][33];
    const int widx = blockIdx.x - 1024;          // 0..2047
    const int e = widx >> 8, rem = widx & 255;
    const int k0 = (rem >> 4) * 32, n0 = (rem & 15) * 32;
    const int ty = tid >> 5, tx = tid & 31;
    const float* src = W + ((long)e * DD + k0) * OUTD + n0;
#pragma unroll
    for (int j = 0; j < 4; ++j)
      tl[ty + j * 8][tx] = src[(long)(ty + j * 8) * OUTD + tx];
    __syncthreads();
    unsigned short* dst = WT + ((long)e * OUTD + n0) * DD + k0;
#pragma unroll
    for (int j = 0; j < 4; ++j)
      dst[(long)(ty + j * 8) * DD + tx] = f2bf(tl[tx][ty + j * 8]);
    return;
  }
  if (tid < 32) eo[blockIdx.x * 32 + tid] = -1;                   // 1024*32 = 32768
  if (blockIdx.x == 0 && tid >= 64 && tid < 64 + BB * EE) counts[tid - 64] = 0;
  const int lane = tid & 63;
  const int w    = tid >> 6;
  float4 g0[8], g1[8];
  const float* gb = gw + (lane * 8) * EE;
#pragma unroll
  for (int q = 0; q < 8; ++q) {
    g0[q] = *(const float4*)(gb + q * EE);
    g1[q] = *(const float4*)(gb + q * EE + 4);
  }
  const long row0 = (long)blockIdx.x * 32 + w * 8;
  for (int i = 0; i < 8; ++i) {
    const long row = row0 + i;
    const float* xr = x + row * DD + lane * 8;
    float4 xa = *(const float4*)(xr);
    float4 xb = *(const float4*)(xr + 4);
    float xv[8] = {xa.x, xa.y, xa.z, xa.w, xb.x, xb.y, xb.z, xb.w};
    s16x8 xo;
#pragma unroll
    for (int j = 0; j < 8; ++j) xo[j] = (short)f2bf(xv[j]);
    *(s16x8*)(xbf + row * DD + lane * 8) = xo;

    float acc[8] = {0.f,0.f,0.f,0.f,0.f,0.f,0.f,0.f};
#pragma unroll
    for (int q = 0; q < 8; ++q) {
      acc[0] += xv[q] * g0[q].x; acc[1] += xv[q] * g0[q].y;
      acc[2] += xv[q] * g0[q].z; acc[3] += xv[q] * g0[q].w;
      acc[4] += xv[q] * g1[q].x; acc[5] += xv[q] * g1[q].y;
      acc[6] += xv[q] * g1[q].z; acc[7] += xv[q] * g1[q].w;
    }
#pragma unroll
    for (int d = 1; d <= 4; d <<= 1) {
#pragma unroll
      for (int e = 0; e < 8; ++e) {
        float tmp = __shfl_xor(acc[e], d);
        acc[e] += ((lane & d) == (e & d)) ? tmp : 0.f;
      }
    }
    float v = acc[0];
#pragma unroll
    for (int e = 1; e < 8; ++e) v = ((lane & 7) == e) ? acc[e] : v;
#pragma unroll
    for (int d = 8; d < 64; d <<= 1) v += __shfl_xor(v, d);
    if (lane < 8) t0[row * EE + lane] = logf(fmaxf(v, EPSV));
  }
}

// ---- linear-domain fused Sinkhorn: 1 block/batch, 8 rows/thread, NO global sync ----
__global__ __launch_bounds__(1024) void k_sink5(const float* __restrict__ t0,
                                                float* __restrict__ R,
                                                float* __restrict__ C) {
  const int b = blockIdx.x;            // 4 blocks
  const int tid = threadIdx.x;         // 1024
  const int wv = tid >> 6, ln = tid & 63;
  const float* tb = t0 + (long)b * NN * EE;
  float E[8][8], u[8], dl[8];
  __shared__ float ws[16][8];
  __shared__ float Csh[8];
  __shared__ float Ssh[8];
#pragma unroll
  for (int j = 0; j < 8; ++j) {
    const float* p = tb + (long)(j * 1024 + tid) * EE;
    float4 a = *(const float4*)p, b4 = *(const float4*)(p + 4);
    E[j][0] = expf(a.x);  E[j][1] = expf(a.y);
    E[j][2] = expf(a.z);  E[j][3] = expf(a.w);
    E[j][4] = expf(b4.x); E[j][5] = expf(b4.y);
    E[j][6] = expf(b4.z); E[j][7] = expf(b4.w);
    u[j] = 1.f;
  }
  for (int it = 0; it < ITERS; ++it) {
    float P[8] = {0.f,0.f,0.f,0.f,0.f,0.f,0.f,0.f};
#pragma unroll
    for (int j = 0; j < 8; ++j)
#pragma unroll
      for (int e = 0; e < 8; ++e) P[e] += E[j][e] * u[j];
#pragma unroll
    for (int d = 1; d <= 4; d <<= 1) {
#pragma unroll
      for (int e = 0; e < 8; ++e) {
        float tmp = __shfl_xor(P[e], d);
        P[e] += ((ln & d) == (e & d)) ? tmp : 0.f;
      }
    }
    float pv = P[0];
#pragma unroll
    for (int e = 1; e < 8; ++e) pv = ((ln & 7) == e) ? P[e] : pv;
#pragma unroll
    for (int d = 8; d < 64; d <<= 1) pv += __shfl_xor(pv, d);
    if (ln < 8) ws[wv][ln] = pv;
    __syncthreads();
    if (tid < 64) {
      const int q = ln >> 3, e = ln & 7;
      float s = ws[q][e] + ws[q + 8][e];
#pragma unroll
      for (int d = 8; d < 64; d <<= 1) s += __shfl_xor(s, d);
      if (ln < 8) { Csh[ln] = 1.f / s; Ssh[ln] = s; }
    }
    __syncthreads();
    float vv[8];
#pragma unroll
    for (int e = 0; e < 8; ++e) vv[e] = Csh[e];
#pragma unroll
    for (int j = 0; j < 8; ++j) {
      float d0 = E[j][0] * vv[0];
#pragma unroll
      for (int e = 1; e < 8; ++e) d0 += E[j][e] * vv[e];
      dl[j] = d0;
      u[j] = 1.f / d0;
    }
    __syncthreads();   // protect ws/Csh WAR before next iteration's writes
  }
#pragma unroll
  for (int j = 0; j < 8; ++j) R[(long)b * NN + j * 1024 + tid] = logf(dl[j]);
  if (tid < 8) C[b * EE + tid] = logf(Ssh[tid]);
}

// ---------------- exact top-1024 per (b,e) column via radix select ----------------
__global__ __launch_bounds__(1024) void k_topk(const float* __restrict__ t0,
                                               const float* __restrict__ R,
                                               int* __restrict__ expert_of) {
  __shared__ unsigned key[NN];
  __shared__ int hist[256];
  __shared__ int bcast[2];
  __shared__ int wsum[16];
  const int b = blockIdx.x >> 3, e = blockIdx.x & 7;
  const int tid = threadIdx.x;
  const int wv = tid >> 6, ln = tid & 63;
  const float* t = t0 + (long)b * NN * EE + e;
  const float* Rb = R + b * NN;
  for (int n = tid; n < NN; n += 1024) {
    float f = t[n * EE] - Rb[n];
    unsigned u = __float_as_uint(f);
    u = (u & 0x80000000u) ? ~u : (u | 0x80000000u);   // sortable: larger u = larger f
    key[n] = u;
  }
  __syncthreads();
  unsigned prefix = 0, mask = 0;
  int k = TOPM;
  for (int shift = 24; shift >= 0; shift -= 8) {
    if (tid < 256) hist[tid] = 0;
    __syncthreads();
    for (int n = tid; n < NN; n += 1024) {
      unsigned u = key[n];
      if ((u & mask) == prefix) atomicAdd(&hist[(u >> shift) & 255], 1);
    }
    __syncthreads();
    for (int d = 1; d < 256; d <<= 1) {
      int add = 0;
      if (tid < 256 - d) add = hist[tid + d];
      __syncthreads();
      if (tid < 256) hist[tid] += add;
      __syncthreads();
    }
    if (tid < 256) {
      int sv = hist[tid];
      int sv1 = (tid < 255) ? hist[tid + 1] : 0;
      if (sv >= k && sv1 < k) { bcast[0] = k - sv1; bcast[1] = tid; }
    }
    __syncthreads();
    k = bcast[0];
    prefix |= ((unsigned)bcast[1]) << shift;
    mask |= (255u << shift);
    __syncthreads();
  }
  const unsigned theta = prefix;
  const int need = k;
  const int base = tid * 8;
  int c = 0;
#pragma unroll
  for (int j = 0; j < 8; ++j) if (key[base + j] == theta) ++c;
  int inc = c;
#pragma unroll
  for (int d = 1; d < 64; d <<= 1) {
    int o = __shfl_up(inc, d);
    if (ln >= d) inc += o;
  }
  if (ln == 63) wsum[wv] = inc;
  __syncthreads();
  if (tid == 0) {
    int runv = 0;
    for (int i = 0; i < 16; ++i) { int t2 = wsum[i]; wsum[i] = runv; runv += t2; }
  }
  __syncthreads();
  int run = wsum[wv] + inc - c;
  int* eo = expert_of + b * NN;
  for (int j = 0; j < 8; ++j) {
    int n = base + j;
    unsigned u = key[n];
    bool sel = false;
    if (u > theta) sel = true;
    else if (u == theta) { if (run < need) sel = true; ++run; }
    if (sel) atomicMax(&eo[n], e);     // np scatter: largest expert index wins
  }
}

// ---- compact per-(b,e) token lists + gate values: LDS hist + 1 global atomic/(block,e) ----
__global__ __launch_bounds__(256) void k_build(const int* __restrict__ expert_of,
                                               const float* __restrict__ t0,
                                               const float* __restrict__ R,
                                               const float* __restrict__ C,
                                               int* __restrict__ counts,
                                               int* __restrict__ lists,
                                               float* __restrict__ gvals) {
  __shared__ int hist8[8], base8[8];
  const int tid = threadIdx.x;
  if (tid < 8) hist8[tid] = 0;
  __syncthreads();
  const long i = (long)blockIdx.x * 256 + tid;     // grid=128; block within one batch
  const int b = (int)(i >> 13);
  const int e = expert_of[i];
  int lpos = -1;
  if (e >= 0) lpos = atomicAdd(&hist8[e], 1);      // LDS atomic: ns-scale
  __syncthreads();
  if (tid < 8 && hist8[tid] > 0)
    base8[tid] = atomicAdd(&counts[b * EE + tid], hist8[tid]);  // 1 RMW per (block,e)
  __syncthreads();
  if (e >= 0) {
    const int n = (int)(i & (NN - 1));
    const int be = b * EE + e;
    const int slot = be * TOPM + base8[e] + lpos;
    lists[slot] = n;
    gvals[slot] = expf(t0[i * EE + e] - C[be] - R[i]);
  }
}

// ---------------- zero output rows of unselected tokens ----------------
__global__ __launch_bounds__(256) void k_zero(const int* __restrict__ eo,
                                              float* __restrict__ out) {
  const int row = blockIdx.x * 4 + (threadIdx.x >> 6);
  if (eo[row] >= 0) return;
  const int ln = threadIdx.x & 63;
  float4 z = make_float4(0.f, 0.f, 0.f, 0.f);
  float4* p = (float4*)(out + (long)row * OUTD) + ln;
  p[0] = z; p[64] = z;
}

// ---------------- gathered bf16 MFMA GEMM: out[tok,:] = g * x[tok,:] @ W[e] ----------------
__global__ __launch_bounds__(256) void k_gemm(const unsigned short* __restrict__ xbf,
                                              const unsigned short* __restrict__ WT,
                                              const int* __restrict__ counts,
                                              const int* __restrict__ lists,
                                              const float* __restrict__ gvals,
                                              float* __restrict__ out) {
  const int be = blockIdx.z;
  const int b = be >> 3, e = be & 7;
  const int cnt = counts[be];
  const int r0 = blockIdx.y * 128;
  if (r0 >= cnt) return;
  const int c0 = blockIdx.x * 128;

  __shared__ unsigned short As[128 * 32];   // [row][k] bf16, k-slot XOR-swizzled
  __shared__ unsigned short Bs[128 * 32];   // [col][k] bf16 (from WT), same swizzle
  __shared__ int   rowTok[128];
  __shared__ float rowG[128];

  const int tid = threadIdx.x;
  if (tid < 128) {
    int r = r0 + tid;
    rowTok[tid] = (r < cnt) ? lists[be * TOPM + r] : -1;
    rowG[tid]   = (r < cnt) ? gvals[be * TOPM + r] : 0.f;
  }
  __syncthreads();

  const int w = tid >> 6, l = tid & 63;
  const int c_a = 2 * w, c_b = 2 * w + 1;
  const int rr = l >> 2;
  const int slot = l & 3;
  const int ra0 = c_a * 16 + rr;
  const int ra1 = c_b * 16 + rr;
  const int kg0 = slot ^ ((ra0 >> 1) & 3);   // pre-swizzled global k-chunk (involution)
  const int kg1 = slot ^ ((ra1 >> 1) & 3);
  int tA0 = rowTok[ra0]; if (tA0 < 0) tA0 = 0;
  int tA1 = rowTok[ra1]; if (tA1 < 0) tA1 = 0;
  const unsigned short* gA0 = xbf + ((long)b * NN + tA0) * DD + kg0 * 8;
  const unsigned short* gA1 = xbf + ((long)b * NN + tA1) * DD + kg1 * 8;
  const unsigned short* gB0 = WT + ((long)e * OUTD + c0 + ra0) * DD + kg0 * 8;
  const unsigned short* gB1 = WT + ((long)e * OUTD + c0 + ra1) * DD + kg1 * 8;
  unsigned short* lA0 = As + c_a * 512;
  unsigned short* lA1 = As + c_b * 512;
  unsigned short* lB0 = Bs + c_a * 512;
  unsigned short* lB1 = Bs + c_b * 512;

  const int wr = w >> 1, wc = w & 1;
  const int fr = l & 15, fq = l >> 4;
  int aoff[4], boff[4];
#pragma unroll
  for (int m = 0; m < 4; ++m) {
    int row = wr * 64 + m * 16 + fr;
    aoff[m] = row * 32 + (fq ^ ((row >> 1) & 3)) * 8;   // swizzled read matches staged layout
    int col = wc * 64 + m * 16 + fr;
    boff[m] = col * 32 + (fq ^ ((col >> 1) & 3)) * 8;
  }

  f32x4 acc[4][4] = {};

  gll16(gA0, lA0); gll16(gA1, lA1);
  gll16(gB0, lB0); gll16(gB1, lB1);

  for (int ks = 0; ks < 16; ++ks) {
    __syncthreads();
    s16x8 af[4], bfr[4];
#pragma unroll
    for (int m = 0; m < 4; ++m) af[m] = *(const s16x8*)(As + aoff[m]);
#pragma unroll
    for (int n = 0; n < 4; ++n) bfr[n] = *(const s16x8*)(Bs + boff[n]);
    __syncthreads();
    if (ks < 15) {
      int off = (ks + 1) * 32;
      gll16(gA0 + off, lA0); gll16(gA1 + off, lA1);
      gll16(gB0 + off, lB0); gll16(gB1 + off, lB1);
    }
#pragma unroll
    for (int m = 0; m < 4; ++m)
#pragma unroll
      for (int n = 0; n < 4; ++n)
        acc[m][n] = __builtin_amdgcn_mfma_f32_16x16x32_bf16(af[m], bfr[n], acc[m][n], 0, 0, 0);
  }

  // epilogue: C/D layout col=lane&15, row=(lane>>4)*4+reg
#pragma unroll
  for (int m = 0; m < 4; ++m) {
    int rbase = wr * 64 + m * 16 + fq * 4;
    int tok[4]; float g[4];
#pragma unroll
    for (int j = 0; j < 4; ++j) { tok[j] = rowTok[rbase + j]; g[j] = rowG[rbase + j]; }
#pragma unroll
    for (int n = 0; n < 4; ++n) {
      int col = c0 + wc * 64 + n * 16 + fr;
#pragma unroll
      for (int j = 0; j < 4; ++j) {
        if (tok[j] >= 0)
          out[((long)b * NN + tok[j]) * OUTD + col] = acc[m][n][j] * g[j];
      }
    }
  }
}

extern "C" void kernel_launch(void* const* d_in, const int* in_sizes, int n_in,
                              void* d_out, int out_size, void* d_ws, size_t ws_size,
                              hipStream_t stream) {
  const float* x  = (const float*)d_in[0];
  const float* gw = (const float*)d_in[1];
  const float* ex = (const float*)d_in[2];
  float* out = (float*)d_out;

  char* wsb = (char*)d_ws;
  float*          t0     = (float*)(wsb);                          // 1 MiB
  unsigned short* xbf    = (unsigned short*)(wsb + (1l << 20));    // 32 MiB
  unsigned short* WT     = (unsigned short*)(wsb + (33l << 20));   // 4 MiB
  const long base = 37l << 20;
  float*          R      = (float*)(wsb + base);                           // 128 KiB
  int*            eo     = (int*)  (wsb + base + (128l << 10));            // 128 KiB
  int*            lists  = (int*)  (wsb + base + (256l << 10));            // 128 KiB
  float*          gvals  = (float*)(wsb + base + (384l << 10));            // 128 KiB
  float*          C      = (float*)(wsb + base + (512l << 10));            // 32 B
  int*            counts = (int*)  (wsb + base + (512l << 10) + 1024);     // 128 B

  k_gate<<<1024 + 2048, 256, 0, stream>>>(x, gw, t0, xbf, eo, counts, ex, WT);
  k_sink5<<<BB, 1024, 0, stream>>>(t0, R, C);
  k_topk<<<BB * EE, 1024, 0, stream>>>(t0, R, eo);
  k_build<<<(BB * NN) / 256, 256, 0, stream>>>(eo, t0, R, C, counts, lists, gvals);
  k_zero<<<(BB * NN) / 4, 256, 0, stream>>>(eo, out);
  k_gemm<<<dim3(OUTD / 128, TOPM / 128, BB * EE), 256, 0, stream>>>(xbf, WT, counts, lists, gvals, out);
}

// Round 10
// 118.930 us; speedup vs baseline: 4.2182x; 1.0381x over previous
//
#include <hip/hip_runtime.h>
#include <hip/hip_bf16.h>

#define BB 4
#define NN 8192
#define DD 512
#define EE 8
#define OUTD 512
#define TOPM 1024
#define EPSV 1e-6f
#define ITERS 8

using s16x8 = __attribute__((ext_vector_type(8))) short;
using f32x4 = __attribute__((ext_vector_type(4))) float;
typedef unsigned long long u64;

__device__ __forceinline__ unsigned short f2bf(float f) {
  unsigned u = __float_as_uint(f);
  return (unsigned short)((u + 0x7FFFu + ((u >> 16) & 1u)) >> 16);
}

__device__ __forceinline__ void gll16(const void* g, void* l) {
  __builtin_amdgcn_global_load_lds((const __attribute__((address_space(1))) void*)g,
                                   (__attribute__((address_space(3))) void*)l, 16, 0, 0);
}

// ---- gate logits -> t0 = log(max(x@gw, eps)); x -> bf16; expert transpose;
// ---- gw hoisted to VGPRs (8 rows/wave); init eo/counts ----
__global__ __launch_bounds__(256) void k_gate(const float* __restrict__ x,
                                              const float* __restrict__ gw,
                                              float* __restrict__ t0,
                                              unsigned short* __restrict__ xbf,
                                              int* __restrict__ eo,
                                              int* __restrict__ counts,
                                              const float* __restrict__ W,
                                              unsigned short* __restrict__ WT) {
  const int tid = threadIdx.x;
  if (blockIdx.x >= 1024) {
    // ---- expert transpose: f32 [e][k][n] -> bf16 [e][n][k], 32x32 tiles ----
    __shared__ float tl[32][33];
    const int widx = blockIdx.x - 1024;          // 0..2047
    const int e = widx >> 8, rem = widx & 255;
    const int k0 = (rem >> 4) * 32, n0 = (rem & 15) * 32;
    const int ty = tid >> 5, tx = tid & 31;
    const float* src = W + ((long)e * DD + k0) * OUTD + n0;
#pragma unroll
    for (int j = 0; j < 4; ++j)
      tl[ty + j * 8][tx] = src[(long)(ty + j * 8) * OUTD + tx];
    __syncthreads();
    unsigned short* dst = WT + ((long)e * OUTD + n0) * DD + k0;
#pragma unroll
    for (int j = 0; j < 4; ++j)
      dst[(long)(ty + j * 8) * DD + tx] = f2bf(tl[tx][ty + j * 8]);
    return;
  }
  if (tid < 32) eo[blockIdx.x * 32 + tid] = -1;                   // 1024*32 = 32768
  if (blockIdx.x == 0 && tid >= 64 && tid < 64 + BB * EE) counts[tid - 64] = 0;
  const int lane = tid & 63;
  const int w    = tid >> 6;
  float4 g0[8], g1[8];
  const float* gb = gw + (lane * 8) * EE;
#pragma unroll
  for (int q = 0; q < 8; ++q) {
    g0[q] = *(const float4*)(gb + q * EE);
    g1[q] = *(const float4*)(gb + q * EE + 4);
  }
  const long row0 = (long)blockIdx.x * 32 + w * 8;
  for (int i = 0; i < 8; ++i) {
    const long row = row0 + i;
    const float* xr = x + row * DD + lane * 8;
    float4 xa = *(const float4*)(xr);
    float4 xb = *(const float4*)(xr + 4);
    float xv[8] = {xa.x, xa.y, xa.z, xa.w, xb.x, xb.y, xb.z, xb.w};
    s16x8 xo;
#pragma unroll
    for (int j = 0; j < 8; ++j) xo[j] = (short)f2bf(xv[j]);
    *(s16x8*)(xbf + row * DD + lane * 8) = xo;

    float acc[8] = {0.f,0.f,0.f,0.f,0.f,0.f,0.f,0.f};
#pragma unroll
    for (int q = 0; q < 8; ++q) {
      acc[0] += xv[q] * g0[q].x; acc[1] += xv[q] * g0[q].y;
      acc[2] += xv[q] * g0[q].z; acc[3] += xv[q] * g0[q].w;
      acc[4] += xv[q] * g1[q].x; acc[5] += xv[q] * g1[q].y;
      acc[6] += xv[q] * g1[q].z; acc[7] += xv[q] * g1[q].w;
    }
#pragma unroll
    for (int d = 1; d <= 4; d <<= 1) {
#pragma unroll
      for (int e = 0; e < 8; ++e) {
        float tmp = __shfl_xor(acc[e], d);
        acc[e] += ((lane & d) == (e & d)) ? tmp : 0.f;
      }
    }
    float v = acc[0];
#pragma unroll
    for (int e = 1; e < 8; ++e) v = ((lane & 7) == e) ? acc[e] : v;
#pragma unroll
    for (int d = 8; d < 64; d <<= 1) v += __shfl_xor(v, d);
    if (lane < 8) t0[row * EE + lane] = logf(fmaxf(v, EPSV));
  }
}

// ---- linear-domain fused Sinkhorn: 1 block/batch, 8 rows/thread, NO global sync ----
__global__ __launch_bounds__(1024) void k_sink5(const float* __restrict__ t0,
                                                float* __restrict__ R,
                                                float* __restrict__ C) {
  const int b = blockIdx.x;            // 4 blocks
  const int tid = threadIdx.x;         // 1024
  const int wv = tid >> 6, ln = tid & 63;
  const float* tb = t0 + (long)b * NN * EE;
  float E[8][8], u[8], dl[8];
  __shared__ float ws[16][8];
  __shared__ float Csh[8];
  __shared__ float Ssh[8];
#pragma unroll
  for (int j = 0; j < 8; ++j) {
    const float* p = tb + (long)(j * 1024 + tid) * EE;
    float4 a = *(const float4*)p, b4 = *(const float4*)(p + 4);
    E[j][0] = expf(a.x);  E[j][1] = expf(a.y);
    E[j][2] = expf(a.z);  E[j][3] = expf(a.w);
    E[j][4] = expf(b4.x); E[j][5] = expf(b4.y);
    E[j][6] = expf(b4.z); E[j][7] = expf(b4.w);
    u[j] = 1.f;
  }
  for (int it = 0; it < ITERS; ++it) {
    float P[8] = {0.f,0.f,0.f,0.f,0.f,0.f,0.f,0.f};
#pragma unroll
    for (int j = 0; j < 8; ++j)
#pragma unroll
      for (int e = 0; e < 8; ++e) P[e] += E[j][e] * u[j];
#pragma unroll
    for (int d = 1; d <= 4; d <<= 1) {
#pragma unroll
      for (int e = 0; e < 8; ++e) {
        float tmp = __shfl_xor(P[e], d);
        P[e] += ((ln & d) == (e & d)) ? tmp : 0.f;
      }
    }
    float pv = P[0];
#pragma unroll
    for (int e = 1; e < 8; ++e) pv = ((ln & 7) == e) ? P[e] : pv;
#pragma unroll
    for (int d = 8; d < 64; d <<= 1) pv += __shfl_xor(pv, d);
    if (ln < 8) ws[wv][ln] = pv;
    __syncthreads();
    if (tid < 64) {
      const int q = ln >> 3, e = ln & 7;
      float s = ws[q][e] + ws[q + 8][e];
#pragma unroll
      for (int d = 8; d < 64; d <<= 1) s += __shfl_xor(s, d);
      if (ln < 8) { Csh[ln] = 1.f / s; Ssh[ln] = s; }
    }
    __syncthreads();
    float vv[8];
#pragma unroll
    for (int e = 0; e < 8; ++e) vv[e] = Csh[e];
#pragma unroll
    for (int j = 0; j < 8; ++j) {
      float d0 = E[j][0] * vv[0];
#pragma unroll
      for (int e = 1; e < 8; ++e) d0 += E[j][e] * vv[e];
      dl[j] = d0;
      u[j] = 1.f / d0;
    }
    __syncthreads();   // protect ws/Csh WAR before next iteration's writes
  }
#pragma unroll
  for (int j = 0; j < 8; ++j) R[(long)b * NN + j * 1024 + tid] = logf(dl[j]);
  if (tid < 8) C[b * EE + tid] = logf(Ssh[tid]);
}

// ---------------- exact top-1024 per (b,e) column via radix select ----------------
__global__ __launch_bounds__(1024) void k_topk(const float* __restrict__ t0,
                                               const float* __restrict__ R,
                                               int* __restrict__ expert_of) {
  __shared__ unsigned key[NN];
  __shared__ int hist[256];
  __shared__ int bcast[2];
  __shared__ int wsum[16];
  const int b = blockIdx.x >> 3, e = blockIdx.x & 7;
  const int tid = threadIdx.x;
  const int wv = tid >> 6, ln = tid & 63;
  const float* t = t0 + (long)b * NN * EE + e;
  const float* Rb = R + b * NN;
  for (int n = tid; n < NN; n += 1024) {
    float f = t[n * EE] - Rb[n];
    unsigned u = __float_as_uint(f);
    u = (u & 0x80000000u) ? ~u : (u | 0x80000000u);   // sortable: larger u = larger f
    key[n] = u;
  }
  __syncthreads();
  unsigned prefix = 0, mask = 0;
  int k = TOPM;
  for (int shift = 24; shift >= 0; shift -= 8) {
    if (tid < 256) hist[tid] = 0;
    __syncthreads();
    for (int n = tid; n < NN; n += 1024) {
      unsigned u = key[n];
      if ((u & mask) == prefix) atomicAdd(&hist[(u >> shift) & 255], 1);
    }
    __syncthreads();
    for (int d = 1; d < 256; d <<= 1) {
      int add = 0;
      if (tid < 256 - d) add = hist[tid + d];
      __syncthreads();
      if (tid < 256) hist[tid] += add;
      __syncthreads();
    }
    if (tid < 256) {
      int sv = hist[tid];
      int sv1 = (tid < 255) ? hist[tid + 1] : 0;
      if (sv >= k && sv1 < k) { bcast[0] = k - sv1; bcast[1] = tid; }
    }
    __syncthreads();
    k = bcast[0];
    prefix |= ((unsigned)bcast[1]) << shift;
    mask |= (255u << shift);
    __syncthreads();
  }
  const unsigned theta = prefix;
  const int need = k;
  const int base = tid * 8;
  int c = 0;
#pragma unroll
  for (int j = 0; j < 8; ++j) if (key[base + j] == theta) ++c;
  int inc = c;
#pragma unroll
  for (int d = 1; d < 64; d <<= 1) {
    int o = __shfl_up(inc, d);
    if (ln >= d) inc += o;
  }
  if (ln == 63) wsum[wv] = inc;
  __syncthreads();
  if (tid == 0) {
    int runv = 0;
    for (int i = 0; i < 16; ++i) { int t2 = wsum[i]; wsum[i] = runv; runv += t2; }
  }
  __syncthreads();
  int run = wsum[wv] + inc - c;
  int* eo = expert_of + b * NN;
  for (int j = 0; j < 8; ++j) {
    int n = base + j;
    unsigned u = key[n];
    bool sel = false;
    if (u > theta) sel = true;
    else if (u == theta) { if (run < need) sel = true; ++run; }
    if (sel) atomicMax(&eo[n], e);     // np scatter: largest expert index wins
  }
}

// ---- compact per-(b,e) token lists + gate values: LDS hist + 1 global atomic/(block,e) ----
__global__ __launch_bounds__(256) void k_build(const int* __restrict__ expert_of,
                                               const float* __restrict__ t0,
                                               const float* __restrict__ R,
                                               const float* __restrict__ C,
                                               int* __restrict__ counts,
                                               int* __restrict__ lists,
                                               float* __restrict__ gvals) {
  __shared__ int hist8[8], base8[8];
  const int tid = threadIdx.x;
  if (tid < 8) hist8[tid] = 0;
  __syncthreads();
  const long i = (long)blockIdx.x * 256 + tid;     // grid=128; block within one batch
  const int b = (int)(i >> 13);
  const int e = expert_of[i];
  int lpos = -1;
  if (e >= 0) lpos = atomicAdd(&hist8[e], 1);      // LDS atomic: ns-scale
  __syncthreads();
  if (tid < 8 && hist8[tid] > 0)
    base8[tid] = atomicAdd(&counts[b * EE + tid], hist8[tid]);  // 1 RMW per (block,e)
  __syncthreads();
  if (e >= 0) {
    const int n = (int)(i & (NN - 1));
    const int be = b * EE + e;
    const int slot = be * TOPM + base8[e] + lpos;
    lists[slot] = n;
    gvals[slot] = expf(t0[i * EE + e] - C[be] - R[i]);
  }
}

// ---------------- zero output rows of unselected tokens ----------------
__global__ __launch_bounds__(256) void k_zero(const int* __restrict__ eo,
                                              float* __restrict__ out) {
  const int row = blockIdx.x * 4 + (threadIdx.x >> 6);
  if (eo[row] >= 0) return;
  const int ln = threadIdx.x & 63;
  float4 z = make_float4(0.f, 0.f, 0.f, 0.f);
  float4* p = (float4*)(out + (long)row * OUTD) + ln;
  p[0] = z; p[64] = z;
}

// ---- gathered bf16 MFMA GEMM, BK=64, XCD-colocated A-sharing blocks ----
// LDS layout: [row][64k] bf16 (128 B/row), 16B-slot XOR-swizzled: slot ^= (row&7).
// Staged via gll16 with pre-swizzled per-lane GLOBAL source (linear LDS dest), read
// back with the same XOR (both-sides-or-neither).
__global__ __launch_bounds__(256) void k_gemm(const unsigned short* __restrict__ xbf,
                                              const unsigned short* __restrict__ WT,
                                              const int* __restrict__ counts,
                                              const int* __restrict__ lists,
                                              const float* __restrict__ gvals,
                                              float* __restrict__ out) {
  // id = x*256 + be*8 + y: the 4 x-variants (sharing the A-tile) differ by 256 ≡ 0 mod 8
  // -> same XCD -> A-tile served from that XCD's L2 after first fetch.
  const int id = blockIdx.x;                 // 1024
  const int xq = id >> 8;                    // 0..3  col tile
  const int be = (id >> 3) & 31;             // b*8+e
  const int yq = id & 7;                     // 0..7  row tile
  const int b = be >> 3, e = be & 7;
  const int cnt = counts[be];
  const int r0 = yq * 128;
  if (r0 >= cnt) return;
  const int c0 = xq * 128;

  __shared__ unsigned short As[128 * 64];    // 16 KiB
  __shared__ unsigned short Bs[128 * 64];    // 16 KiB
  __shared__ int   rowTok[128];
  __shared__ float rowG[128];

  const int tid = threadIdx.x;
  if (tid < 128) {
    int r = r0 + tid;
    rowTok[tid] = (r < cnt) ? lists[be * TOPM + r] : -1;
    rowG[tid]   = (r < cnt) ? gvals[be * TOPM + r] : 0.f;
  }
  __syncthreads();

  const int w = tid >> 6, l = tid & 63;
  // staging: issue c covers rows [w*32 + c*8, +8); lane -> row w*32+c*8+(l>>3), 16B-slot l&7
  const int rbase = w * 32 + (l >> 3);
  const int sL = l & 7;
  const unsigned short* xb_b = xbf + (long)b * NN * DD;
  const unsigned short* wt_e = WT + (long)e * OUTD * DD;
  int tokc[4]; int sGa[4], sGb[4];
#pragma unroll
  for (int c = 0; c < 4; ++c) {
    int r = rbase + c * 8;
    int tk = rowTok[r]; if (tk < 0) tk = 0;
    tokc[c] = tk;
    sGa[c] = (sL ^ (r & 7)) * 8;             // pre-swizzled global k-slot (elems)
    sGb[c] = sGa[c];
  }

  // MFMA fragment read offsets (elems), swizzled to match the staged layout
  const int wr = w >> 1, wc = w & 1;
  const int fr = l & 15, fq = l >> 4;
  int aoff[4][2], boff[4][2];
#pragma unroll
  for (int m = 0; m < 4; ++m) {
#pragma unroll
    for (int kk = 0; kk < 2; ++kk) {
      int row = wr * 64 + m * 16 + fr;
      aoff[m][kk] = row * 64 + (((fq + 4 * kk) ^ (row & 7)) * 8);
      int col = wc * 64 + m * 16 + fr;
      boff[m][kk] = col * 64 + (((fq + 4 * kk) ^ (col & 7)) * 8);
    }
  }

  f32x4 acc[4][4] = {};

#define STAGE(kb) {                                                          \
    int ko = (kb) * 64;                                                      \
    _Pragma("unroll")                                                        \
    for (int c = 0; c < 4; ++c) {                                            \
      int r = rbase + c * 8;                                                 \
      gll16(xb_b + (long)tokc[c] * DD + ko + sGa[c],                         \
            As + (w * 32 + c * 8) * 64);                                     \
      gll16(wt_e + (long)(c0 + r) * DD + ko + sGb[c],                        \
            Bs + (w * 32 + c * 8) * 64);                                     \
    }                                                                        \
  }

  STAGE(0);
  for (int kb = 0; kb < 8; ++kb) {
    __syncthreads();                         // staging visible (vmcnt drained at barrier)
    s16x8 af[4][2], bf_[4][2];
#pragma unroll
    for (int m = 0; m < 4; ++m) {
      af[m][0] = *(const s16x8*)(As + aoff[m][0]);
      af[m][1] = *(const s16x8*)(As + aoff[m][1]);
      bf_[m][0] = *(const s16x8*)(Bs + boff[m][0]);
      bf_[m][1] = *(const s16x8*)(Bs + boff[m][1]);
    }
    __syncthreads();                         // frags in regs; safe to restage
    if (kb < 7) STAGE(kb + 1);
#pragma unroll
    for (int kk = 0; kk < 2; ++kk)
#pragma unroll
      for (int m = 0; m < 4; ++m)
#pragma unroll
        for (int n = 0; n < 4; ++n)
          acc[m][n] = __builtin_amdgcn_mfma_f32_16x16x32_bf16(af[m][kk], bf_[n][kk], acc[m][n], 0, 0, 0);
  }
#undef STAGE

  // epilogue: C/D layout col=lane&15, row=(lane>>4)*4+reg
#pragma unroll
  for (int m = 0; m < 4; ++m) {
    int rbase2 = wr * 64 + m * 16 + fq * 4;
    int tok[4]; float g[4];
#pragma unroll
    for (int j = 0; j < 4; ++j) { tok[j] = rowTok[rbase2 + j]; g[j] = rowG[rbase2 + j]; }
#pragma unroll
    for (int n = 0; n < 4; ++n) {
      int col = c0 + wc * 64 + n * 16 + fr;
#pragma unroll
      for (int j = 0; j < 4; ++j) {
        if (tok[j] >= 0)
          out[((long)b * NN + tok[j]) * OUTD + col] = acc[m][n][j] * g[j];
      }
    }
  }
}

extern "C" void kernel_launch(void* const* d_in, const int* in_sizes, int n_in,
                              void* d_out, int out_size, void* d_ws, size_t ws_size,
                              hipStream_t stream) {
  const float* x  = (const float*)d_in[0];
  const float* gw = (const float*)d_in[1];
  const float* ex = (const float*)d_in[2];
  float* out = (float*)d_out;

  char* wsb = (char*)d_ws;
  float*          t0     = (float*)(wsb);                          // 1 MiB
  unsigned short* xbf    = (unsigned short*)(wsb + (1l << 20));    // 32 MiB
  unsigned short* WT     = (unsigned short*)(wsb + (33l << 20));   // 4 MiB
  const long base = 37l << 20;
  float*          R      = (float*)(wsb + base);                           // 128 KiB
  int*            eo     = (int*)  (wsb + base + (128l << 10));            // 128 KiB
  int*            lists  = (int*)  (wsb + base + (256l << 10));            // 128 KiB
  float*          gvals  = (float*)(wsb + base + (384l << 10));            // 128 KiB
  float*          C      = (float*)(wsb + base + (512l << 10));            // 32 B
  int*            counts = (int*)  (wsb + base + (512l << 10) + 1024);     // 128 B

  k_gate<<<1024 + 2048, 256, 0, stream>>>(x, gw, t0, xbf, eo, counts, ex, WT);
  k_sink5<<<BB, 1024, 0, stream>>>(t0, R, C);
  k_topk<<<BB * EE, 1024, 0, stream>>>(t0, R, eo);
  k_build<<<(BB * NN) / 256, 256, 0, stream>>>(eo, t0, R, C, counts, lists, gvals);
  k_zero<<<(BB * NN) / 4, 256, 0, stream>>>(eo, out);
  k_gemm<<<1024, 256, 0, stream>>>(xbf, WT, counts, lists, gvals, out);
}

// Round 11
// 114.338 us; speedup vs baseline: 4.3876x; 1.0402x over previous
//
#include <hip/hip_runtime.h>
#include <hip/hip_bf16.h>

#define BB 4
#define NN 8192
#define DD 512
#define EE 8
#define OUTD 512
#define TOPM 1024
#define EPSV 1e-6f
#define ITERS 8

using s16x8 = __attribute__((ext_vector_type(8))) short;
using f32x4 = __attribute__((ext_vector_type(4))) float;
typedef unsigned long long u64;

__device__ __forceinline__ unsigned short f2bf(float f) {
  unsigned u = __float_as_uint(f);
  return (unsigned short)((u + 0x7FFFu + ((u >> 16) & 1u)) >> 16);
}

__device__ __forceinline__ void gll16(const void* g, void* l) {
  __builtin_amdgcn_global_load_lds((const __attribute__((address_space(1))) void*)g,
                                   (__attribute__((address_space(3))) void*)l, 16, 0, 0);
}

// ---- gate logits -> t0 = log(max(x@gw, eps)); x -> bf16; expert transpose;
// ---- 4 rows/wave batched loads + 10-shuffle fold; init eo/counts ----
__global__ __launch_bounds__(256) void k_gate(const float* __restrict__ x,
                                              const float* __restrict__ gw,
                                              float* __restrict__ t0,
                                              unsigned short* __restrict__ xbf,
                                              int* __restrict__ eo,
                                              int* __restrict__ counts,
                                              const float* __restrict__ W,
                                              unsigned short* __restrict__ WT) {
  const int tid = threadIdx.x;
  if (blockIdx.x >= 2048) {
    // ---- expert transpose: f32 [e][k][n] -> bf16 [e][n][k], 32x32 tiles ----
    __shared__ float tl[32][33];
    const int widx = blockIdx.x - 2048;          // 0..2047
    const int e = widx >> 8, rem = widx & 255;
    const int k0 = (rem >> 4) * 32, n0 = (rem & 15) * 32;
    const int ty = tid >> 5, tx = tid & 31;
    const float* src = W + ((long)e * DD + k0) * OUTD + n0;
#pragma unroll
    for (int j = 0; j < 4; ++j)
      tl[ty + j * 8][tx] = src[(long)(ty + j * 8) * OUTD + tx];
    __syncthreads();
    unsigned short* dst = WT + ((long)e * OUTD + n0) * DD + k0;
#pragma unroll
    for (int j = 0; j < 4; ++j)
      dst[(long)(ty + j * 8) * DD + tx] = f2bf(tl[tx][ty + j * 8]);
    return;
  }
  if (tid < 16) eo[blockIdx.x * 16 + tid] = -1;                   // 2048*16 = 32768
  if (blockIdx.x == 0 && tid >= 64 && tid < 64 + BB * EE) counts[tid - 64] = 0;
  const int lane = tid & 63;
  const int w    = tid >> 6;
  // hoist gw into regs: lane covers k in [lane*8, lane*8+8)
  float4 g0[8], g1[8];
  const float* gb = gw + (lane * 8) * EE;
#pragma unroll
  for (int q = 0; q < 8; ++q) {
    g0[q] = *(const float4*)(gb + q * EE);
    g1[q] = *(const float4*)(gb + q * EE + 4);
  }
  const long row0 = (long)blockIdx.x * 16 + w * 4;
  // batch all loads first: 8 outstanding 16B loads/lane
  float4 xa[4], xb[4];
#pragma unroll
  for (int i = 0; i < 4; ++i) {
    const float* xr = x + (row0 + i) * DD + lane * 8;
    xa[i] = *(const float4*)(xr);
    xb[i] = *(const float4*)(xr + 4);
  }
  float vout[4];
#pragma unroll
  for (int i = 0; i < 4; ++i) {
    float xv[8] = {xa[i].x, xa[i].y, xa[i].z, xa[i].w,
                   xb[i].x, xb[i].y, xb[i].z, xb[i].w};
    s16x8 xo;
#pragma unroll
    for (int j = 0; j < 8; ++j) xo[j] = (short)f2bf(xv[j]);
    *(s16x8*)(xbf + (row0 + i) * DD + lane * 8) = xo;

    float acc[8] = {0.f,0.f,0.f,0.f,0.f,0.f,0.f,0.f};
#pragma unroll
    for (int q = 0; q < 8; ++q) {
      acc[0] += xv[q] * g0[q].x; acc[1] += xv[q] * g0[q].y;
      acc[2] += xv[q] * g0[q].z; acc[3] += xv[q] * g0[q].w;
      acc[4] += xv[q] * g1[q].x; acc[5] += xv[q] * g1[q].y;
      acc[6] += xv[q] * g1[q].z; acc[7] += xv[q] * g1[q].w;
    }
    // select+shuffle halving fold: 8 arrays -> e=lane&7 in 7 shuffles, +3 wide
    const bool o1 = lane & 1;
    float own, oth, b0, b1, b2, b3, c0, c1, v;
    own = o1 ? acc[1] : acc[0]; oth = o1 ? acc[0] : acc[1];
    b0 = own + __shfl_xor(oth, 1);
    own = o1 ? acc[3] : acc[2]; oth = o1 ? acc[2] : acc[3];
    b1 = own + __shfl_xor(oth, 1);
    own = o1 ? acc[5] : acc[4]; oth = o1 ? acc[4] : acc[5];
    b2 = own + __shfl_xor(oth, 1);
    own = o1 ? acc[7] : acc[6]; oth = o1 ? acc[6] : acc[7];
    b3 = own + __shfl_xor(oth, 1);
    const bool o2 = lane & 2;
    own = o2 ? b1 : b0; oth = o2 ? b0 : b1;
    c0 = own + __shfl_xor(oth, 2);
    own = o2 ? b3 : b2; oth = o2 ? b2 : b3;
    c1 = own + __shfl_xor(oth, 2);
    const bool o4 = lane & 4;
    own = o4 ? c1 : c0; oth = o4 ? c0 : c1;
    v = own + __shfl_xor(oth, 4);
    v += __shfl_xor(v, 8);
    v += __shfl_xor(v, 16);
    v += __shfl_xor(v, 32);
    vout[i] = v;              // e = lane&7, all lanes
  }
  // coalesced t0 store: lanes 0..31 cover 4 rows x 8 experts
  const int gsel = lane >> 3;
  float vsel = vout[0];
  vsel = (gsel == 1) ? vout[1] : vsel;
  vsel = (gsel == 2) ? vout[2] : vsel;
  vsel = (gsel == 3) ? vout[3] : vsel;
  if (lane < 32) t0[row0 * EE + lane] = logf(fmaxf(vsel, EPSV));
}

// ---- linear-domain fused Sinkhorn: 1 block/batch, 8 rows/thread, NO global sync ----
__global__ __launch_bounds__(1024) void k_sink5(const float* __restrict__ t0,
                                                float* __restrict__ R,
                                                float* __restrict__ C) {
  const int b = blockIdx.x;            // 4 blocks
  const int tid = threadIdx.x;         // 1024
  const int wv = tid >> 6, ln = tid & 63;
  const float* tb = t0 + (long)b * NN * EE;
  float E[8][8], u[8], dl[8];
  __shared__ float ws[16][8];
  __shared__ float Csh[8];
  __shared__ float Ssh[8];
#pragma unroll
  for (int j = 0; j < 8; ++j) {
    const float* p = tb + (long)(j * 1024 + tid) * EE;
    float4 a = *(const float4*)p, b4 = *(const float4*)(p + 4);
    E[j][0] = expf(a.x);  E[j][1] = expf(a.y);
    E[j][2] = expf(a.z);  E[j][3] = expf(a.w);
    E[j][4] = expf(b4.x); E[j][5] = expf(b4.y);
    E[j][6] = expf(b4.z); E[j][7] = expf(b4.w);
    u[j] = 1.f;
  }
  for (int it = 0; it < ITERS; ++it) {
    float P[8] = {0.f,0.f,0.f,0.f,0.f,0.f,0.f,0.f};
#pragma unroll
    for (int j = 0; j < 8; ++j)
#pragma unroll
      for (int e = 0; e < 8; ++e) P[e] += E[j][e] * u[j];
#pragma unroll
    for (int d = 1; d <= 4; d <<= 1) {
#pragma unroll
      for (int e = 0; e < 8; ++e) {
        float tmp = __shfl_xor(P[e], d);
        P[e] += ((ln & d) == (e & d)) ? tmp : 0.f;
      }
    }
    float pv = P[0];
#pragma unroll
    for (int e = 1; e < 8; ++e) pv = ((ln & 7) == e) ? P[e] : pv;
#pragma unroll
    for (int d = 8; d < 64; d <<= 1) pv += __shfl_xor(pv, d);
    if (ln < 8) ws[wv][ln] = pv;
    __syncthreads();
    if (tid < 64) {
      const int q = ln >> 3, e = ln & 7;
      float s = ws[q][e] + ws[q + 8][e];
#pragma unroll
      for (int d = 8; d < 64; d <<= 1) s += __shfl_xor(s, d);
      if (ln < 8) { Csh[ln] = 1.f / s; Ssh[ln] = s; }
    }
    __syncthreads();
    float vv[8];
#pragma unroll
    for (int e = 0; e < 8; ++e) vv[e] = Csh[e];
#pragma unroll
    for (int j = 0; j < 8; ++j) {
      float d0 = E[j][0] * vv[0];
#pragma unroll
      for (int e = 1; e < 8; ++e) d0 += E[j][e] * vv[e];
      dl[j] = d0;
      u[j] = 1.f / d0;
    }
    __syncthreads();   // protect ws/Csh WAR before next iteration's writes
  }
#pragma unroll
  for (int j = 0; j < 8; ++j) R[(long)b * NN + j * 1024 + tid] = logf(dl[j]);
  if (tid < 8) C[b * EE + tid] = logf(Ssh[tid]);
}

// ---------------- exact top-1024 per (b,e) column via radix select ----------------
__global__ __launch_bounds__(1024) void k_topk(const float* __restrict__ t0,
                                               const float* __restrict__ R,
                                               int* __restrict__ expert_of) {
  __shared__ unsigned key[NN];
  __shared__ int hist[256];
  __shared__ int bcast[2];
  __shared__ int wsum[16];
  const int b = blockIdx.x >> 3, e = blockIdx.x & 7;
  const int tid = threadIdx.x;
  const int wv = tid >> 6, ln = tid & 63;
  const float* t = t0 + (long)b * NN * EE + e;
  const float* Rb = R + b * NN;
  for (int n = tid; n < NN; n += 1024) {
    float f = t[n * EE] - Rb[n];
    unsigned u = __float_as_uint(f);
    u = (u & 0x80000000u) ? ~u : (u | 0x80000000u);   // sortable: larger u = larger f
    key[n] = u;
  }
  __syncthreads();
  unsigned prefix = 0, mask = 0;
  int k = TOPM;
  for (int shift = 24; shift >= 0; shift -= 8) {
    if (tid < 256) hist[tid] = 0;
    __syncthreads();
    for (int n = tid; n < NN; n += 1024) {
      unsigned u = key[n];
      if ((u & mask) == prefix) atomicAdd(&hist[(u >> shift) & 255], 1);
    }
    __syncthreads();
    for (int d = 1; d < 256; d <<= 1) {
      int add = 0;
      if (tid < 256 - d) add = hist[tid + d];
      __syncthreads();
      if (tid < 256) hist[tid] += add;
      __syncthreads();
    }
    if (tid < 256) {
      int sv = hist[tid];
      int sv1 = (tid < 255) ? hist[tid + 1] : 0;
      if (sv >= k && sv1 < k) { bcast[0] = k - sv1; bcast[1] = tid; }
    }
    __syncthreads();
    k = bcast[0];
    prefix |= ((unsigned)bcast[1]) << shift;
    mask |= (255u << shift);
    __syncthreads();
  }
  const unsigned theta = prefix;
  const int need = k;
  const int base = tid * 8;
  int c = 0;
#pragma unroll
  for (int j = 0; j < 8; ++j) if (key[base + j] == theta) ++c;
  int inc = c;
#pragma unroll
  for (int d = 1; d < 64; d <<= 1) {
    int o = __shfl_up(inc, d);
    if (ln >= d) inc += o;
  }
  if (ln == 63) wsum[wv] = inc;
  __syncthreads();
  if (tid == 0) {
    int runv = 0;
    for (int i = 0; i < 16; ++i) { int t2 = wsum[i]; wsum[i] = runv; runv += t2; }
  }
  __syncthreads();
  int run = wsum[wv] + inc - c;
  int* eo = expert_of + b * NN;
  for (int j = 0; j < 8; ++j) {
    int n = base + j;
    unsigned u = key[n];
    bool sel = false;
    if (u > theta) sel = true;
    else if (u == theta) { if (run < need) sel = true; ++run; }
    if (sel) atomicMax(&eo[n], e);     // np scatter: largest expert index wins
  }
}

// ---- compact per-(b,e) token lists + gate values: LDS hist + 1 global atomic/(block,e) ----
__global__ __launch_bounds__(256) void k_build(const int* __restrict__ expert_of,
                                               const float* __restrict__ t0,
                                               const float* __restrict__ R,
                                               const float* __restrict__ C,
                                               int* __restrict__ counts,
                                               int* __restrict__ lists,
                                               float* __restrict__ gvals) {
  __shared__ int hist8[8], base8[8];
  const int tid = threadIdx.x;
  if (tid < 8) hist8[tid] = 0;
  __syncthreads();
  const long i = (long)blockIdx.x * 256 + tid;     // grid=128; block within one batch
  const int b = (int)(i >> 13);
  const int e = expert_of[i];
  int lpos = -1;
  if (e >= 0) lpos = atomicAdd(&hist8[e], 1);      // LDS atomic: ns-scale
  __syncthreads();
  if (tid < 8 && hist8[tid] > 0)
    base8[tid] = atomicAdd(&counts[b * EE + tid], hist8[tid]);  // 1 RMW per (block,e)
  __syncthreads();
  if (e >= 0) {
    const int n = (int)(i & (NN - 1));
    const int be = b * EE + e;
    const int slot = be * TOPM + base8[e] + lpos;
    lists[slot] = n;
    gvals[slot] = expf(t0[i * EE + e] - C[be] - R[i]);
  }
}

// ---------------- zero output rows of unselected tokens ----------------
__global__ __launch_bounds__(256) void k_zero(const int* __restrict__ eo,
                                              float* __restrict__ out) {
  const int row = blockIdx.x * 4 + (threadIdx.x >> 6);
  if (eo[row] >= 0) return;
  const int ln = threadIdx.x & 63;
  float4 z = make_float4(0.f, 0.f, 0.f, 0.f);
  float4* p = (float4*)(out + (long)row * OUTD) + ln;
  p[0] = z; p[64] = z;
}

// ---- gathered bf16 MFMA GEMM, BK=64, XCD-colocated A-sharing blocks ----
__global__ __launch_bounds__(256) void k_gemm(const unsigned short* __restrict__ xbf,
                                              const unsigned short* __restrict__ WT,
                                              const int* __restrict__ counts,
                                              const int* __restrict__ lists,
                                              const float* __restrict__ gvals,
                                              float* __restrict__ out) {
  const int id = blockIdx.x;                 // 1024
  const int xq = id >> 8;                    // 0..3  col tile
  const int be = (id >> 3) & 31;             // b*8+e
  const int yq = id & 7;                     // 0..7  row tile
  const int b = be >> 3, e = be & 7;
  const int cnt = counts[be];
  const int r0 = yq * 128;
  if (r0 >= cnt) return;
  const int c0 = xq * 128;

  __shared__ unsigned short As[128 * 64];    // 16 KiB
  __shared__ unsigned short Bs[128 * 64];    // 16 KiB
  __shared__ int   rowTok[128];
  __shared__ float rowG[128];

  const int tid = threadIdx.x;
  if (tid < 128) {
    int r = r0 + tid;
    rowTok[tid] = (r < cnt) ? lists[be * TOPM + r] : -1;
    rowG[tid]   = (r < cnt) ? gvals[be * TOPM + r] : 0.f;
  }
  __syncthreads();

  const int w = tid >> 6, l = tid & 63;
  const int rbase = w * 32 + (l >> 3);
  const int sL = l & 7;
  const unsigned short* xb_b = xbf + (long)b * NN * DD;
  const unsigned short* wt_e = WT + (long)e * OUTD * DD;
  int tokc[4]; int sGa[4], sGb[4];
#pragma unroll
  for (int c = 0; c < 4; ++c) {
    int r = rbase + c * 8;
    int tk = rowTok[r]; if (tk < 0) tk = 0;
    tokc[c] = tk;
    sGa[c] = (sL ^ (r & 7)) * 8;             // pre-swizzled global k-slot (elems)
    sGb[c] = sGa[c];
  }

  const int wr = w >> 1, wc = w & 1;
  const int fr = l & 15, fq = l >> 4;
  int aoff[4][2], boff[4][2];
#pragma unroll
  for (int m = 0; m < 4; ++m) {
#pragma unroll
    for (int kk = 0; kk < 2; ++kk) {
      int row = wr * 64 + m * 16 + fr;
      aoff[m][kk] = row * 64 + (((fq + 4 * kk) ^ (row & 7)) * 8);
      int col = wc * 64 + m * 16 + fr;
      boff[m][kk] = col * 64 + (((fq + 4 * kk) ^ (col & 7)) * 8);
    }
  }

  f32x4 acc[4][4] = {};

#define STAGE(kb) {                                                          \
    int ko = (kb) * 64;                                                      \
    _Pragma("unroll")                                                        \
    for (int c = 0; c < 4; ++c) {                                            \
      int r = rbase + c * 8;                                                 \
      gll16(xb_b + (long)tokc[c] * DD + ko + sGa[c],                         \
            As + (w * 32 + c * 8) * 64);                                     \
      gll16(wt_e + (long)(c0 + r) * DD + ko + sGb[c],                        \
            Bs + (w * 32 + c * 8) * 64);                                     \
    }                                                                        \
  }

  STAGE(0);
  for (int kb = 0; kb < 8; ++kb) {
    __syncthreads();
    s16x8 af[4][2], bf_[4][2];
#pragma unroll
    for (int m = 0; m < 4; ++m) {
      af[m][0] = *(const s16x8*)(As + aoff[m][0]);
      af[m][1] = *(const s16x8*)(As + aoff[m][1]);
      bf_[m][0] = *(const s16x8*)(Bs + boff[m][0]);
      bf_[m][1] = *(const s16x8*)(Bs + boff[m][1]);
    }
    __syncthreads();
    if (kb < 7) STAGE(kb + 1);
#pragma unroll
    for (int kk = 0; kk < 2; ++kk)
#pragma unroll
      for (int m = 0; m < 4; ++m)
#pragma unroll
        for (int n = 0; n < 4; ++n)
          acc[m][n] = __builtin_amdgcn_mfma_f32_16x16x32_bf16(af[m][kk], bf_[n][kk], acc[m][n], 0, 0, 0);
  }
#undef STAGE

  // epilogue: C/D layout col=lane&15, row=(lane>>4)*4+reg
#pragma unroll
  for (int m = 0; m < 4; ++m) {
    int rbase2 = wr * 64 + m * 16 + fq * 4;
    int tok[4]; float g[4];
#pragma unroll
    for (int j = 0; j < 4; ++j) { tok[j] = rowTok[rbase2 + j]; g[j] = rowG[rbase2 + j]; }
#pragma unroll
    for (int n = 0; n < 4; ++n) {
      int col = c0 + wc * 64 + n * 16 + fr;
#pragma unroll
      for (int j = 0; j < 4; ++j) {
        if (tok[j] >= 0)
          out[((long)b * NN + tok[j]) * OUTD + col] = acc[m][n][j] * g[j];
      }
    }
  }
}

extern "C" void kernel_launch(void* const* d_in, const int* in_sizes, int n_in,
                              void* d_out, int out_size, void* d_ws, size_t ws_size,
                              hipStream_t stream) {
  const float* x  = (const float*)d_in[0];
  const float* gw = (const float*)d_in[1];
  const float* ex = (const float*)d_in[2];
  float* out = (float*)d_out;

  char* wsb = (char*)d_ws;
  float*          t0     = (float*)(wsb);                          // 1 MiB
  unsigned short* xbf    = (unsigned short*)(wsb + (1l << 20));    // 32 MiB
  unsigned short* WT     = (unsigned short*)(wsb + (33l << 20));   // 4 MiB
  const long base = 37l << 20;
  float*          R      = (float*)(wsb + base);                           // 128 KiB
  int*            eo     = (int*)  (wsb + base + (128l << 10));            // 128 KiB
  int*            lists  = (int*)  (wsb + base + (256l << 10));            // 128 KiB
  float*          gvals  = (float*)(wsb + base + (384l << 10));            // 128 KiB
  float*          C      = (float*)(wsb + base + (512l << 10));            // 32 B
  int*            counts = (int*)  (wsb + base + (512l << 10) + 1024);     // 128 B

  k_gate<<<2048 + 2048, 256, 0, stream>>>(x, gw, t0, xbf, eo, counts, ex, WT);
  k_sink5<<<BB, 1024, 0, stream>>>(t0, R, C);
  k_topk<<<BB * EE, 1024, 0, stream>>>(t0, R, eo);
  k_build<<<(BB * NN) / 256, 256, 0, stream>>>(eo, t0, R, C, counts, lists, gvals);
  k_zero<<<(BB * NN) / 4, 256, 0, stream>>>(eo, out);
  k_gemm<<<1024, 256, 0, stream>>>(xbf, WT, counts, lists, gvals, out);
}